// Round 1
// baseline (755.068 us; speedup 1.0000x reference)
//
#include <hip/hip_runtime.h>

#define N_NODES   50000
#define N_EDGES   625000
#define HIDDEN    128
#define NUM_GRAPHS 128
#define EPS_GN    1e-5f

// ---- workspace layout (in floats) ----
// h     : [0,            6,400,000)   node @ W.T
// deg   : [6,400,000,    6,450,000)   degree -> dinv (in place)
// gsum  : [6,450,000,    6,466,384)   per-graph per-col sums -> mean (in place)
// gcnt  : [6,466,384,    6,466,512)   per-graph node counts
// gvar  : [6,466,512,    6,482,896)   per-graph per-col centered^2 sums
#define H_OFF    0
#define DEG_OFF  6400000
#define GSUM_OFF 6450000
#define GCNT_OFF 6466384
#define GVAR_OFF 6466512

// ---------------- GEMM: h = x @ W.T  (x:[N,128], W:[128,128] row-major [out,in]) ----------------
__global__ __launch_bounds__(256) void gemm_xwt(const float* __restrict__ x,
                                                const float* __restrict__ W,
                                                float* __restrict__ h) {
    __shared__ float xs[64][33];
    __shared__ float ws[128][33];
    const int t = threadIdx.x;
    const int row0 = blockIdx.x * 64;
    const int tx = t & 15;      // col group
    const int ty = t >> 4;      // row group
    float acc[4][8];
#pragma unroll
    for (int i = 0; i < 4; ++i)
#pragma unroll
        for (int j = 0; j < 8; ++j) acc[i][j] = 0.f;

    for (int kt = 0; kt < HIDDEN; kt += 32) {
        // stage x tile: 64 rows x 32 k
#pragma unroll
        for (int p = 0; p < 2; ++p) {
            int r  = (t >> 3) + p * 32;       // 0..63
            int kq = (t & 7) * 4;             // 0..28
            int grow = row0 + r;
            float4 v = make_float4(0.f, 0.f, 0.f, 0.f);
            if (grow < N_NODES) v = *(const float4*)(x + (size_t)grow * HIDDEN + kt + kq);
            xs[r][kq] = v.x; xs[r][kq + 1] = v.y; xs[r][kq + 2] = v.z; xs[r][kq + 3] = v.w;
        }
        // stage W tile: 128 rows x 32 k
#pragma unroll
        for (int p = 0; p < 4; ++p) {
            int c  = (t >> 3) + p * 32;       // 0..127
            int kq = (t & 7) * 4;
            float4 v = *(const float4*)(W + (size_t)c * HIDDEN + kt + kq);
            ws[c][kq] = v.x; ws[c][kq + 1] = v.y; ws[c][kq + 2] = v.z; ws[c][kq + 3] = v.w;
        }
        __syncthreads();
#pragma unroll
        for (int kk = 0; kk < 32; ++kk) {
            float xr[4], wr[8];
#pragma unroll
            for (int i = 0; i < 4; ++i) xr[i] = xs[ty + 16 * i][kk];
#pragma unroll
            for (int j = 0; j < 8; ++j) wr[j] = ws[tx + 16 * j][kk];
#pragma unroll
            for (int i = 0; i < 4; ++i)
#pragma unroll
                for (int j = 0; j < 8; ++j) acc[i][j] = fmaf(xr[i], wr[j], acc[i][j]);
        }
        __syncthreads();
    }
#pragma unroll
    for (int i = 0; i < 4; ++i) {
        int grow = row0 + ty + 16 * i;
        if (grow < N_NODES) {
#pragma unroll
            for (int j = 0; j < 8; ++j)
                h[(size_t)grow * HIDDEN + tx + 16 * j] = acc[i][j];
        }
    }
}

// ---------------- degree init to 1.0 (self loop weight) ----------------
__global__ void deg_init(float* __restrict__ deg) {
    int n = blockIdx.x * blockDim.x + threadIdx.x;
    if (n < N_NODES) deg[n] = 1.0f;
}

// ---------------- deg[dst] += w ----------------
__global__ void deg_accum(const int* __restrict__ dst, const float* __restrict__ w,
                          float* __restrict__ deg) {
    int e = blockIdx.x * blockDim.x + threadIdx.x;
    if (e < N_EDGES) atomicAdd(&deg[dst[e]], w[e]);
}

// ---------------- dinv = rsqrt(deg) (deg >= 1 always) ----------------
__global__ void deg_rsqrt(float* __restrict__ deg) {
    int n = blockIdx.x * blockDim.x + threadIdx.x;
    if (n < N_NODES) deg[n] = rsqrtf(deg[n]);
}

// ---------------- scatter: out[d,:] += dinv[s]*w*dinv[d] * h[s,:] ----------------
__global__ __launch_bounds__(256) void edge_scatter(const int* __restrict__ src,
                                                    const int* __restrict__ dst,
                                                    const float* __restrict__ w,
                                                    const float* __restrict__ dinv,
                                                    const float* __restrict__ h,
                                                    float* __restrict__ out) {
    const int t = threadIdx.x;
    const int e = blockIdx.x * 2 + (t >> 7);
    const int c = t & 127;
    if (e >= N_EDGES) return;
    const int s = src[e];
    const int d = dst[e];
    const float norm = dinv[s] * w[e] * dinv[d];
    atomicAdd(out + (size_t)d * HIDDEN + c, norm * h[(size_t)s * HIDDEN + c]);
}

// ---------------- finalize GCN (+self loop, +bias) and accumulate graph sums ----------------
__global__ __launch_bounds__(256) void gcn_finalize(float* __restrict__ out,
                                                    const float* __restrict__ h,
                                                    const float* __restrict__ dinv,
                                                    const float* __restrict__ b,
                                                    const int* __restrict__ batch,
                                                    float* __restrict__ gsum,
                                                    float* __restrict__ gcnt) {
    int idx = blockIdx.x * blockDim.x + threadIdx.x;
    if (idx >= N_NODES * HIDDEN) return;
    int n = idx >> 7;
    int c = idx & 127;
    float di = dinv[n];
    float val = out[idx] + di * di * h[idx] + b[c];
    out[idx] = val;
    int g = batch[n];
    atomicAdd(&gsum[g * HIDDEN + c], val);
    if (c == 0) atomicAdd(&gcnt[g], 1.0f);
}

// ---------------- gsum -> mean ----------------
__global__ void graph_mean(float* __restrict__ gsum, const float* __restrict__ gcnt) {
    int idx = blockIdx.x * blockDim.x + threadIdx.x;
    if (idx < NUM_GRAPHS * HIDDEN)
        gsum[idx] /= fmaxf(gcnt[idx >> 7], 1.0f);
}

// ---------------- var accumulation ----------------
__global__ __launch_bounds__(256) void graph_var(const float* __restrict__ out,
                                                 const float* __restrict__ mean,
                                                 const float* __restrict__ ms,
                                                 const int* __restrict__ batch,
                                                 float* __restrict__ gvar) {
    int idx = blockIdx.x * blockDim.x + threadIdx.x;
    if (idx >= N_NODES * HIDDEN) return;
    int n = idx >> 7;
    int c = idx & 127;
    int g = batch[n];
    float cen = out[idx] - ms[c] * mean[g * HIDDEN + c];
    atomicAdd(&gvar[g * HIDDEN + c], cen * cen);
}

// ---------------- normalize + affine + relu ----------------
__global__ __launch_bounds__(256) void gn_final(float* __restrict__ out,
                                                const float* __restrict__ mean,
                                                const float* __restrict__ gvar,
                                                const float* __restrict__ gcnt,
                                                const float* __restrict__ ms,
                                                const float* __restrict__ gw,
                                                const float* __restrict__ gb,
                                                const int* __restrict__ batch) {
    int idx = blockIdx.x * blockDim.x + threadIdx.x;
    if (idx >= N_NODES * HIDDEN) return;
    int n = idx >> 7;
    int c = idx & 127;
    int g = batch[n];
    float cnt = fmaxf(gcnt[g], 1.0f);
    float var = gvar[g * HIDDEN + c] / cnt;
    float inv = rsqrtf(var + EPS_GN);
    float cen = out[idx] - ms[c] * mean[g * HIDDEN + c];
    float y = gw[c] * cen * inv + gb[c];
    out[idx] = fmaxf(y, 0.f);
}

extern "C" void kernel_launch(void* const* d_in, const int* in_sizes, int n_in,
                              void* d_out, int out_size, void* d_ws, size_t ws_size,
                              hipStream_t stream) {
    const float* node  = (const float*)d_in[0];
    const int*   ei    = (const int*)d_in[1];      // [2, E] flat
    const float* eattr = (const float*)d_in[2];
    const int*   batch = (const int*)d_in[3];
    const float* W     = (const float*)d_in[4];
    const float* b     = (const float*)d_in[5];
    const float* gnw   = (const float*)d_in[6];
    const float* gnb   = (const float*)d_in[7];
    const float* gnms  = (const float*)d_in[8];
    float* out = (float*)d_out;
    float* ws  = (float*)d_ws;

    const int* src = ei;
    const int* dst = ei + N_EDGES;

    float* h    = ws + H_OFF;
    float* deg  = ws + DEG_OFF;     // becomes dinv in place
    float* gsum = ws + GSUM_OFF;    // becomes mean in place
    float* gcnt = ws + GCNT_OFF;
    float* gvar = ws + GVAR_OFF;

    // zero accumulators (harness poisons, and replays must be deterministic)
    hipMemsetAsync(out, 0, (size_t)N_NODES * HIDDEN * sizeof(float), stream);
    hipMemsetAsync(gsum, 0, (size_t)(NUM_GRAPHS * HIDDEN + NUM_GRAPHS + NUM_GRAPHS * HIDDEN) * sizeof(float), stream);

    deg_init<<<(N_NODES + 255) / 256, 256, 0, stream>>>(deg);
    gemm_xwt<<<(N_NODES + 63) / 64, 256, 0, stream>>>(node, W, h);
    deg_accum<<<(N_EDGES + 255) / 256, 256, 0, stream>>>(dst, eattr, deg);
    deg_rsqrt<<<(N_NODES + 255) / 256, 256, 0, stream>>>(deg);
    edge_scatter<<<(N_EDGES + 1) / 2, 256, 0, stream>>>(src, dst, eattr, deg, h, out);
    gcn_finalize<<<(N_NODES * HIDDEN + 255) / 256, 256, 0, stream>>>(out, h, deg, b, batch, gsum, gcnt);
    graph_mean<<<(NUM_GRAPHS * HIDDEN + 255) / 256, 256, 0, stream>>>(gsum, gcnt);
    graph_var<<<(N_NODES * HIDDEN + 255) / 256, 256, 0, stream>>>(out, gsum, gnms, batch, gvar);
    gn_final<<<(N_NODES * HIDDEN + 255) / 256, 256, 0, stream>>>(out, gsum, gvar, gcnt, gnms, gnw, gnb, batch);

    // copy result to d_out — already there (we used d_out as the accumulator)
    (void)in_sizes; (void)n_in; (void)out_size; (void)ws_size;
}

// Round 2
// 461.952 us; speedup vs baseline: 1.6345x; 1.6345x over previous
//
#include <hip/hip_runtime.h>

#define N_NODES    50000
#define N_EDGES    625000
#define HIDDEN     128
#define NUM_GRAPHS 128
#define EPS_GN     1e-5f

// ---- workspace layout (in floats) ----
#define H_OFF      0          // h: [0, 6,400,000)
#define DEG_OFF    6400000    // deg->dinv: [6,400,000, 6,450,000)
#define SCALE_OFF  6450000    // [128*128]
#define SHIFT_OFF  6466384    // [128*128]
#define GSTART_OFF 6482768    // int[129]

// ---------------- GEMM: h = x @ W.T ----------------
__global__ __launch_bounds__(256) void gemm_xwt(const float* __restrict__ x,
                                                const float* __restrict__ W,
                                                float* __restrict__ h) {
    __shared__ float xs[64][33];
    __shared__ float ws[128][33];
    const int t = threadIdx.x;
    const int row0 = blockIdx.x * 64;
    const int tx = t & 15;
    const int ty = t >> 4;
    float acc[4][8];
#pragma unroll
    for (int i = 0; i < 4; ++i)
#pragma unroll
        for (int j = 0; j < 8; ++j) acc[i][j] = 0.f;

    for (int kt = 0; kt < HIDDEN; kt += 32) {
#pragma unroll
        for (int p = 0; p < 2; ++p) {
            int r  = (t >> 3) + p * 32;
            int kq = (t & 7) * 4;
            int grow = row0 + r;
            float4 v = make_float4(0.f, 0.f, 0.f, 0.f);
            if (grow < N_NODES) v = *(const float4*)(x + (size_t)grow * HIDDEN + kt + kq);
            xs[r][kq] = v.x; xs[r][kq + 1] = v.y; xs[r][kq + 2] = v.z; xs[r][kq + 3] = v.w;
        }
#pragma unroll
        for (int p = 0; p < 4; ++p) {
            int c  = (t >> 3) + p * 32;
            int kq = (t & 7) * 4;
            float4 v = *(const float4*)(W + (size_t)c * HIDDEN + kt + kq);
            ws[c][kq] = v.x; ws[c][kq + 1] = v.y; ws[c][kq + 2] = v.z; ws[c][kq + 3] = v.w;
        }
        __syncthreads();
#pragma unroll
        for (int kk = 0; kk < 32; ++kk) {
            float xr[4], wr[8];
#pragma unroll
            for (int i = 0; i < 4; ++i) xr[i] = xs[ty + 16 * i][kk];
#pragma unroll
            for (int j = 0; j < 8; ++j) wr[j] = ws[tx + 16 * j][kk];
#pragma unroll
            for (int i = 0; i < 4; ++i)
#pragma unroll
                for (int j = 0; j < 8; ++j) acc[i][j] = fmaf(xr[i], wr[j], acc[i][j]);
        }
        __syncthreads();
    }
#pragma unroll
    for (int i = 0; i < 4; ++i) {
        int grow = row0 + ty + 16 * i;
        if (grow < N_NODES) {
#pragma unroll
            for (int j = 0; j < 8; ++j)
                h[(size_t)grow * HIDDEN + tx + 16 * j] = acc[i][j];
        }
    }
}

// ---------------- degree ----------------
__global__ void deg_init(float* __restrict__ deg) {
    int n = blockIdx.x * blockDim.x + threadIdx.x;
    if (n < N_NODES) deg[n] = 1.0f;
}

__global__ void deg_accum(const int* __restrict__ dst, const float* __restrict__ w,
                          float* __restrict__ deg) {
    int e = blockIdx.x * blockDim.x + threadIdx.x;
    if (e < N_EDGES) atomicAdd(&deg[dst[e]], w[e]);
}

__global__ void deg_rsqrt(float* __restrict__ deg) {
    int n = blockIdx.x * blockDim.x + threadIdx.x;
    if (n < N_NODES) deg[n] = rsqrtf(deg[n]);
}

// ---------------- scatter: out[d,:] += dinv[s]*w*dinv[d] * h[s,:] ----------------
__global__ __launch_bounds__(256) void edge_scatter(const int* __restrict__ src,
                                                    const int* __restrict__ dst,
                                                    const float* __restrict__ w,
                                                    const float* __restrict__ dinv,
                                                    const float* __restrict__ h,
                                                    float* __restrict__ out) {
    const int t = threadIdx.x;
    const int e = blockIdx.x * 2 + (t >> 7);
    const int c = t & 127;
    if (e >= N_EDGES) return;
    const int s = src[e];
    const int d = dst[e];
    const float norm = dinv[s] * w[e] * dinv[d];
    atomicAdd(out + (size_t)d * HIDDEN + c, norm * h[(size_t)s * HIDDEN + c]);
}

// ---------------- finalize GCN (+self loop, +bias), float4, no atomics ----------------
__global__ __launch_bounds__(256) void gcn_finalize(float* __restrict__ out,
                                                    const float* __restrict__ h,
                                                    const float* __restrict__ dinv,
                                                    const float* __restrict__ b) {
    int idx = blockIdx.x * blockDim.x + threadIdx.x;     // over N*32 float4s
    if (idx >= N_NODES * 32) return;
    int n  = idx >> 5;
    int c4 = (idx & 31) * 4;
    float di = dinv[n];
    float sl = di * di;
    float4 o = *(float4*)(out + (size_t)n * HIDDEN + c4);
    float4 hv = *(const float4*)(h + (size_t)n * HIDDEN + c4);
    float4 bv = *(const float4*)(b + c4);
    o.x = fmaf(sl, hv.x, o.x) + bv.x;
    o.y = fmaf(sl, hv.y, o.y) + bv.y;
    o.z = fmaf(sl, hv.z, o.z) + bv.z;
    o.w = fmaf(sl, hv.w, o.w) + bv.w;
    *(float4*)(out + (size_t)n * HIDDEN + c4) = o;
}

// ---------------- graph boundaries from sorted batch ----------------
__global__ void bounds_init(int* __restrict__ gstart) {
    int g = threadIdx.x;
    if (g <= NUM_GRAPHS) gstart[g] = N_NODES;
}

__global__ void bounds_mark(const int* __restrict__ batch, int* __restrict__ gstart) {
    int n = blockIdx.x * blockDim.x + threadIdx.x;
    if (n >= N_NODES) return;
    int b0 = batch[n];
    int prev = (n == 0) ? -1 : batch[n - 1];
    for (int g = prev + 1; g <= b0; ++g) gstart[g] = n;
}

// ---------------- per-graph stats -> scale/shift (one block per graph) ----------------
__global__ __launch_bounds__(256) void graph_stats(const float* __restrict__ out,
                                                   const int* __restrict__ gstart,
                                                   const float* __restrict__ ms,
                                                   const float* __restrict__ gw,
                                                   const float* __restrict__ gb,
                                                   float* __restrict__ scale,
                                                   float* __restrict__ shift) {
    const int g = blockIdx.x;
    const int c = threadIdx.x & 127;
    const int half = threadIdx.x >> 7;
    const int s = gstart[g];
    const int e = gstart[g + 1];
    float sum = 0.f, sq = 0.f;
    for (int n = s + half; n < e; n += 2) {
        float v = out[(size_t)n * HIDDEN + c];
        sum += v;
        sq = fmaf(v, v, sq);
    }
    __shared__ float ssum[2][128], ssq[2][128];
    ssum[half][c] = sum;
    ssq[half][c] = sq;
    __syncthreads();
    if (half == 0) {
        sum += ssum[1][c];
        sq  += ssq[1][c];
        float cnt  = (float)max(e - s, 1);
        float mean = sum / cnt;
        float m2   = sq / cnt;
        float msv  = ms[c];
        float var  = fmaxf(m2 - mean * mean * msv * (2.f - msv), 0.f);
        float a    = gw[c] * rsqrtf(var + EPS_GN);
        scale[g * HIDDEN + c] = a;
        shift[g * HIDDEN + c] = gb[c] - a * msv * mean;
    }
}

// ---------------- normalize + affine + relu, float4 ----------------
__global__ __launch_bounds__(256) void gn_final(float* __restrict__ out,
                                                const float* __restrict__ scale,
                                                const float* __restrict__ shift,
                                                const int* __restrict__ batch) {
    int idx = blockIdx.x * blockDim.x + threadIdx.x;     // over N*32 float4s
    if (idx >= N_NODES * 32) return;
    int n  = idx >> 5;
    int c4 = (idx & 31) * 4;
    int g  = batch[n];
    float4 v  = *(float4*)(out + (size_t)n * HIDDEN + c4);
    float4 a  = *(const float4*)(scale + (size_t)g * HIDDEN + c4);
    float4 s  = *(const float4*)(shift + (size_t)g * HIDDEN + c4);
    v.x = fmaxf(fmaf(a.x, v.x, s.x), 0.f);
    v.y = fmaxf(fmaf(a.y, v.y, s.y), 0.f);
    v.z = fmaxf(fmaf(a.z, v.z, s.z), 0.f);
    v.w = fmaxf(fmaf(a.w, v.w, s.w), 0.f);
    *(float4*)(out + (size_t)n * HIDDEN + c4) = v;
}

extern "C" void kernel_launch(void* const* d_in, const int* in_sizes, int n_in,
                              void* d_out, int out_size, void* d_ws, size_t ws_size,
                              hipStream_t stream) {
    const float* node  = (const float*)d_in[0];
    const int*   ei    = (const int*)d_in[1];
    const float* eattr = (const float*)d_in[2];
    const int*   batch = (const int*)d_in[3];
    const float* W     = (const float*)d_in[4];
    const float* b     = (const float*)d_in[5];
    const float* gnw   = (const float*)d_in[6];
    const float* gnb   = (const float*)d_in[7];
    const float* gnms  = (const float*)d_in[8];
    float* out = (float*)d_out;
    float* ws  = (float*)d_ws;

    const int* src = ei;
    const int* dst = ei + N_EDGES;

    float* h     = ws + H_OFF;
    float* deg   = ws + DEG_OFF;
    float* scale = ws + SCALE_OFF;
    float* shift = ws + SHIFT_OFF;
    int*   gstart = (int*)(ws + GSTART_OFF);

    hipMemsetAsync(out, 0, (size_t)N_NODES * HIDDEN * sizeof(float), stream);

    deg_init<<<(N_NODES + 255) / 256, 256, 0, stream>>>(deg);
    gemm_xwt<<<(N_NODES + 63) / 64, 256, 0, stream>>>(node, W, h);
    deg_accum<<<(N_EDGES + 255) / 256, 256, 0, stream>>>(dst, eattr, deg);
    deg_rsqrt<<<(N_NODES + 255) / 256, 256, 0, stream>>>(deg);
    edge_scatter<<<(N_EDGES + 1) / 2, 256, 0, stream>>>(src, dst, eattr, deg, h, out);
    gcn_finalize<<<(N_NODES * 32 + 255) / 256, 256, 0, stream>>>(out, h, deg, b);
    bounds_init<<<1, NUM_GRAPHS + 1, 0, stream>>>(gstart);
    bounds_mark<<<(N_NODES + 255) / 256, 256, 0, stream>>>(batch, gstart);
    graph_stats<<<NUM_GRAPHS, 256, 0, stream>>>(out, gstart, gnms, gnw, gnb, scale, shift);
    gn_final<<<(N_NODES * 32 + 255) / 256, 256, 0, stream>>>(out, scale, shift, batch);

    (void)in_sizes; (void)n_in; (void)out_size; (void)ws_size;
}

// Round 3
// 263.884 us; speedup vs baseline: 2.8614x; 1.7506x over previous
//
#include <hip/hip_runtime.h>

#define N_NODES    50000
#define N_EDGES    625000
#define HIDDEN     128
#define NUM_GRAPHS 128
#define EPS_GN     1e-5f

// ---- workspace layout (in float/int units of 4B) ----
#define H_OFF      0          // [6,400,000]
#define DEG_OFF    6400000    // [50,000]  deg -> dinv in place
#define SCALE_OFF  6450000    // [16,384]
#define SHIFT_OFF  6466384    // [16,384]
#define GSTART_OFF 6482768    // int[129]
#define ROWS_OFF   6483000    // int[50,001]
#define CNT_OFF    6533100    // int[50,000]
#define BSUM_OFF   6583100    // int[256]
#define BOFF_OFF   6583356    // int[256]
#define ESRC_OFF   6583700    // int[625,000]
#define ENORM_OFF  7208700    // float[625,000]
// total ~7,833,700 * 4B = 31.3 MB

// ---------------- GEMM: h = x @ W.T ----------------
__global__ __launch_bounds__(256) void gemm_xwt(const float* __restrict__ x,
                                                const float* __restrict__ W,
                                                float* __restrict__ h) {
    __shared__ float xs[64][33];
    __shared__ float ws[128][33];
    const int t = threadIdx.x;
    const int row0 = blockIdx.x * 64;
    const int tx = t & 15;
    const int ty = t >> 4;
    float acc[4][8];
#pragma unroll
    for (int i = 0; i < 4; ++i)
#pragma unroll
        for (int j = 0; j < 8; ++j) acc[i][j] = 0.f;

    for (int kt = 0; kt < HIDDEN; kt += 32) {
#pragma unroll
        for (int p = 0; p < 2; ++p) {
            int r  = (t >> 3) + p * 32;
            int kq = (t & 7) * 4;
            int grow = row0 + r;
            float4 v = make_float4(0.f, 0.f, 0.f, 0.f);
            if (grow < N_NODES) v = *(const float4*)(x + (size_t)grow * HIDDEN + kt + kq);
            xs[r][kq] = v.x; xs[r][kq + 1] = v.y; xs[r][kq + 2] = v.z; xs[r][kq + 3] = v.w;
        }
#pragma unroll
        for (int p = 0; p < 4; ++p) {
            int c  = (t >> 3) + p * 32;
            int kq = (t & 7) * 4;
            float4 v = *(const float4*)(W + (size_t)c * HIDDEN + kt + kq);
            ws[c][kq] = v.x; ws[c][kq + 1] = v.y; ws[c][kq + 2] = v.z; ws[c][kq + 3] = v.w;
        }
        __syncthreads();
#pragma unroll
        for (int kk = 0; kk < 32; ++kk) {
            float xr[4], wr[8];
#pragma unroll
            for (int i = 0; i < 4; ++i) xr[i] = xs[ty + 16 * i][kk];
#pragma unroll
            for (int j = 0; j < 8; ++j) wr[j] = ws[tx + 16 * j][kk];
#pragma unroll
            for (int i = 0; i < 4; ++i)
#pragma unroll
                for (int j = 0; j < 8; ++j) acc[i][j] = fmaf(xr[i], wr[j], acc[i][j]);
        }
        __syncthreads();
    }
#pragma unroll
    for (int i = 0; i < 4; ++i) {
        int grow = row0 + ty + 16 * i;
        if (grow < N_NODES) {
#pragma unroll
            for (int j = 0; j < 8; ++j)
                h[(size_t)grow * HIDDEN + tx + 16 * j] = acc[i][j];
        }
    }
}

// ---------------- degree + histogram ----------------
__global__ void deg_init(float* __restrict__ deg) {
    int n = blockIdx.x * blockDim.x + threadIdx.x;
    if (n < N_NODES) deg[n] = 1.0f;   // self-loop weight
}

__global__ void edge_hist(const int* __restrict__ dst, const float* __restrict__ w,
                          int* __restrict__ cnt, float* __restrict__ deg) {
    int e = blockIdx.x * blockDim.x + threadIdx.x;
    if (e >= N_EDGES) return;
    int d = dst[e];
    atomicAdd(&cnt[d], 1);
    atomicAdd(&deg[d], w[e]);
}

__global__ void deg_rsqrt(float* __restrict__ deg) {
    int n = blockIdx.x * blockDim.x + threadIdx.x;
    if (n < N_NODES) deg[n] = rsqrtf(deg[n]);
}

// ---------------- exclusive scan of cnt -> rowstart (3 kernels) ----------------
__global__ void scan_partial(const int* __restrict__ cnt, int* __restrict__ bsum) {
    __shared__ int red[256];
    int i = blockIdx.x * 256 + threadIdx.x;
    red[threadIdx.x] = (i < N_NODES) ? cnt[i] : 0;
    __syncthreads();
    for (int off = 128; off > 0; off >>= 1) {
        if (threadIdx.x < off) red[threadIdx.x] += red[threadIdx.x + off];
        __syncthreads();
    }
    if (threadIdx.x == 0) bsum[blockIdx.x] = red[0];
}

__global__ void scan_bsums(const int* __restrict__ bsum, int* __restrict__ boff, int nblocks) {
    __shared__ int s[256];
    int t = threadIdx.x;
    int v0 = (t < nblocks) ? bsum[t] : 0;
    s[t] = v0;
    __syncthreads();
    for (int off = 1; off < 256; off <<= 1) {
        int v = (t >= off) ? s[t - off] : 0;
        __syncthreads();
        s[t] += v;
        __syncthreads();
    }
    boff[t] = s[t] - v0;   // exclusive
}

__global__ void scan_emit(const int* __restrict__ cnt, const int* __restrict__ boff,
                          int* __restrict__ rowstart) {
    __shared__ int s[256];
    int t = threadIdx.x;
    int i = blockIdx.x * 256 + t;
    int v0 = (i < N_NODES) ? cnt[i] : 0;
    s[t] = v0;
    __syncthreads();
    for (int off = 1; off < 256; off <<= 1) {
        int v = (t >= off) ? s[t - off] : 0;
        __syncthreads();
        s[t] += v;
        __syncthreads();
    }
    if (i < N_NODES) rowstart[i] = boff[blockIdx.x] + s[t] - v0;
    if (i == N_NODES) rowstart[N_NODES] = N_EDGES;
}

// ---------------- fill CSR (countdown slots in cnt) ----------------
__global__ void csr_fill(const int* __restrict__ src, const int* __restrict__ dst,
                         const float* __restrict__ w, const float* __restrict__ dinv,
                         const int* __restrict__ rowstart, int* __restrict__ cnt,
                         int* __restrict__ esrc, float* __restrict__ enorm) {
    int e = blockIdx.x * blockDim.x + threadIdx.x;
    if (e >= N_EDGES) return;
    int s = src[e], d = dst[e];
    int r = atomicSub(&cnt[d], 1) - 1;
    int pos = rowstart[d] + r;
    esrc[pos]  = s;
    enorm[pos] = dinv[s] * w[e] * dinv[d];
}

// ---------------- gather: out[n,:] = sum_e norm*h[src,:] + dinv^2*h[n,:] + b ----------------
__global__ __launch_bounds__(256) void gather_fused(const float* __restrict__ h,
                                                    const int* __restrict__ rowstart,
                                                    const int* __restrict__ esrc,
                                                    const float* __restrict__ enorm,
                                                    const float* __restrict__ dinv,
                                                    const float* __restrict__ b,
                                                    float* __restrict__ out) {
    const int t = threadIdx.x;
    const int n = blockIdx.x * 8 + (t >> 5);     // 8 nodes per block
    if (n >= N_NODES) return;
    const int c4 = (t & 31) * 4;                 // float4 column
    const int s0 = rowstart[n];
    const int e0 = rowstart[n + 1];
    const float di = dinv[n];
    const float sl = di * di;
    float4 hv = *(const float4*)(h + (size_t)n * HIDDEN + c4);
    float4 acc;
    acc.x = sl * hv.x; acc.y = sl * hv.y; acc.z = sl * hv.z; acc.w = sl * hv.w;
    for (int p = s0; p < e0; ++p) {
        int s = esrc[p];
        float nm = enorm[p];
        float4 v = *(const float4*)(h + (size_t)s * HIDDEN + c4);
        acc.x = fmaf(nm, v.x, acc.x);
        acc.y = fmaf(nm, v.y, acc.y);
        acc.z = fmaf(nm, v.z, acc.z);
        acc.w = fmaf(nm, v.w, acc.w);
    }
    float4 bv = *(const float4*)(b + c4);
    acc.x += bv.x; acc.y += bv.y; acc.z += bv.z; acc.w += bv.w;
    *(float4*)(out + (size_t)n * HIDDEN + c4) = acc;
}

// ---------------- graph boundaries from sorted batch ----------------
__global__ void bounds_init(int* __restrict__ gstart) {
    int g = threadIdx.x;
    if (g <= NUM_GRAPHS) gstart[g] = N_NODES;
}

__global__ void bounds_mark(const int* __restrict__ batch, int* __restrict__ gstart) {
    int n = blockIdx.x * blockDim.x + threadIdx.x;
    if (n >= N_NODES) return;
    int b0 = batch[n];
    int prev = (n == 0) ? -1 : batch[n - 1];
    for (int g = prev + 1; g <= b0; ++g) gstart[g] = n;
}

// ---------------- per-graph stats -> scale/shift (4 col-chunks per graph) ----------------
__global__ __launch_bounds__(256) void graph_stats(const float* __restrict__ out,
                                                   const int* __restrict__ gstart,
                                                   const float* __restrict__ ms,
                                                   const float* __restrict__ gw,
                                                   const float* __restrict__ gb,
                                                   float* __restrict__ scale,
                                                   float* __restrict__ shift) {
    const int g = blockIdx.x >> 2;
    const int q = blockIdx.x & 3;
    const int c = q * 32 + (threadIdx.x & 31);
    const int r = threadIdx.x >> 5;              // 0..7
    const int s = gstart[g];
    const int e = gstart[g + 1];
    float sum = 0.f, sq = 0.f;
    for (int n = s + r; n < e; n += 8) {
        float v = out[(size_t)n * HIDDEN + c];
        sum += v;
        sq = fmaf(v, v, sq);
    }
    __shared__ float ssum[8][32], ssq[8][32];
    ssum[r][threadIdx.x & 31] = sum;
    ssq[r][threadIdx.x & 31]  = sq;
    __syncthreads();
    if (r == 0) {
        int l = threadIdx.x & 31;
#pragma unroll
        for (int i = 1; i < 8; ++i) { sum += ssum[i][l]; sq += ssq[i][l]; }
        float cnt  = (float)max(e - s, 1);
        float mean = sum / cnt;
        float m2   = sq / cnt;
        float msv  = ms[c];
        float var  = fmaxf(m2 - mean * mean * msv * (2.f - msv), 0.f);
        float a    = gw[c] * rsqrtf(var + EPS_GN);
        scale[g * HIDDEN + c] = a;
        shift[g * HIDDEN + c] = gb[c] - a * msv * mean;
    }
}

// ---------------- normalize + affine + relu, float4 ----------------
__global__ __launch_bounds__(256) void gn_final(float* __restrict__ out,
                                                const float* __restrict__ scale,
                                                const float* __restrict__ shift,
                                                const int* __restrict__ batch) {
    int idx = blockIdx.x * blockDim.x + threadIdx.x;
    if (idx >= N_NODES * 32) return;
    int n  = idx >> 5;
    int c4 = (idx & 31) * 4;
    int g  = batch[n];
    float4 v  = *(float4*)(out + (size_t)n * HIDDEN + c4);
    float4 a  = *(const float4*)(scale + (size_t)g * HIDDEN + c4);
    float4 s  = *(const float4*)(shift + (size_t)g * HIDDEN + c4);
    v.x = fmaxf(fmaf(a.x, v.x, s.x), 0.f);
    v.y = fmaxf(fmaf(a.y, v.y, s.y), 0.f);
    v.z = fmaxf(fmaf(a.z, v.z, s.z), 0.f);
    v.w = fmaxf(fmaf(a.w, v.w, s.w), 0.f);
    *(float4*)(out + (size_t)n * HIDDEN + c4) = v;
}

extern "C" void kernel_launch(void* const* d_in, const int* in_sizes, int n_in,
                              void* d_out, int out_size, void* d_ws, size_t ws_size,
                              hipStream_t stream) {
    const float* node  = (const float*)d_in[0];
    const int*   ei    = (const int*)d_in[1];
    const float* eattr = (const float*)d_in[2];
    const int*   batch = (const int*)d_in[3];
    const float* W     = (const float*)d_in[4];
    const float* b     = (const float*)d_in[5];
    const float* gnw   = (const float*)d_in[6];
    const float* gnb   = (const float*)d_in[7];
    const float* gnms  = (const float*)d_in[8];
    float* out = (float*)d_out;
    float* ws  = (float*)d_ws;

    const int* src = ei;
    const int* dst = ei + N_EDGES;

    float* h       = ws + H_OFF;
    float* deg     = ws + DEG_OFF;        // -> dinv
    float* scale   = ws + SCALE_OFF;
    float* shift   = ws + SHIFT_OFF;
    int*   gstart  = (int*)(ws + GSTART_OFF);
    int*   rowstart= (int*)(ws + ROWS_OFF);
    int*   cnt     = (int*)(ws + CNT_OFF);
    int*   bsum    = (int*)(ws + BSUM_OFF);
    int*   boff    = (int*)(ws + BOFF_OFF);
    int*   esrc    = (int*)(ws + ESRC_OFF);
    float* enorm   = ws + ENORM_OFF;

    const int NB = (N_NODES + 255) / 256;   // 196

    hipMemsetAsync(cnt, 0, (size_t)N_NODES * sizeof(int), stream);
    deg_init<<<NB, 256, 0, stream>>>(deg);
    gemm_xwt<<<(N_NODES + 63) / 64, 256, 0, stream>>>(node, W, h);
    edge_hist<<<(N_EDGES + 255) / 256, 256, 0, stream>>>(dst, eattr, cnt, deg);
    deg_rsqrt<<<NB, 256, 0, stream>>>(deg);
    scan_partial<<<NB, 256, 0, stream>>>(cnt, bsum);
    scan_bsums<<<1, 256, 0, stream>>>(bsum, boff, NB);
    scan_emit<<<NB, 256, 0, stream>>>(cnt, boff, rowstart);
    csr_fill<<<(N_EDGES + 255) / 256, 256, 0, stream>>>(src, dst, eattr, deg, rowstart, cnt, esrc, enorm);
    gather_fused<<<(N_NODES + 7) / 8, 256, 0, stream>>>(h, rowstart, esrc, enorm, deg, b, out);
    bounds_init<<<1, NUM_GRAPHS + 1, 0, stream>>>(gstart);
    bounds_mark<<<NB, 256, 0, stream>>>(batch, gstart);
    graph_stats<<<NUM_GRAPHS * 4, 256, 0, stream>>>(out, gstart, gnms, gnw, gnb, scale, shift);
    gn_final<<<(N_NODES * 32 + 255) / 256, 256, 0, stream>>>(out, scale, shift, batch);

    (void)in_sizes; (void)n_in; (void)out_size; (void)ws_size;
}

// Round 4
// 218.820 us; speedup vs baseline: 3.4506x; 1.2059x over previous
//
#include <hip/hip_runtime.h>

#define N_NODES    50000
#define N_EDGES    625000
#define HIDDEN     128
#define NUM_GRAPHS 128
#define EPS_GN     1e-5f

typedef __bf16 bf16x8 __attribute__((ext_vector_type(8)));
typedef float  f32x4  __attribute__((ext_vector_type(4)));
typedef unsigned short u16x8 __attribute__((ext_vector_type(8)));
typedef unsigned short u16x4 __attribute__((ext_vector_type(4)));

__device__ inline unsigned short f2b(float f) {
    __bf16 b = (__bf16)f;
    return __builtin_bit_cast(unsigned short, b);
}
__device__ inline float b2f(unsigned short u) {
    unsigned int x = ((unsigned int)u) << 16;
    return __builtin_bit_cast(float, x);
}

// ---- workspace layout (4B units) ----
#define XB_OFF     0          // ushort[6,400,000]  bf16(node)
#define HB_OFF     3200000    // ushort[6,400,000]  bf16(h)
#define WB_OFF     6400000    // ushort[16,384]
#define DEG_OFF    6410000    // float[50,000] -> dinv in place
#define SCALE_OFF  6460000    // float[16,384]
#define SHIFT_OFF  6476384    // float[16,384]
#define GSTART_OFF 6492768    // int[129]
#define ROWS_OFF   6493000    // int[50,001]
#define CNT_OFF    6543100    // int[50,000]
#define BSUM_OFF   6593100    // int[256]
#define BOFF_OFF   6593400    // int[256]
#define ESRC_OFF   6593700    // int[625,000]
#define ENORM_OFF  7218700    // float[625,000]  (end 7,843,700 = 31.4 MB)

// ---------------- f32 -> bf16 convert (8 elems/thread) ----------------
__global__ void cvt_f32_bf16(const float* __restrict__ x, unsigned short* __restrict__ y, int n8) {
    int i = blockIdx.x * blockDim.x + threadIdx.x;
    if (i >= n8) return;
    const float4* p = (const float4*)(x + (size_t)i * 8);
    float4 a = p[0], b = p[1];
    u16x8 u;
    u[0] = f2b(a.x); u[1] = f2b(a.y); u[2] = f2b(a.z); u[3] = f2b(a.w);
    u[4] = f2b(b.x); u[5] = f2b(b.y); u[6] = f2b(b.z); u[7] = f2b(b.w);
    *(u16x8*)(y + (size_t)i * 8) = u;
}

// ---------------- MFMA GEMM: h = x @ W.T, bf16 in, bf16 out, f32 acc ----------------
__global__ __launch_bounds__(256) void gemm_mfma(const unsigned short* __restrict__ xb,
                                                 const unsigned short* __restrict__ wb,
                                                 unsigned short* __restrict__ hb) {
    const int wave = threadIdx.x >> 6;
    const int lane = threadIdx.x & 63;
    const int row0 = blockIdx.x * 64 + wave * 16;
    const int r  = lane & 15;          // A row / B col within tile
    const int ko = (lane >> 4) * 8;    // k offset within 32-wide k-step
    f32x4 acc[8];
#pragma unroll
    for (int t = 0; t < 8; ++t) { acc[t][0] = 0.f; acc[t][1] = 0.f; acc[t][2] = 0.f; acc[t][3] = 0.f; }
    int arow = row0 + r;
    if (arow >= N_NODES) arow = N_NODES - 1;   // clamp; stores are bounds-checked
    const size_t abase = (size_t)arow * HIDDEN + ko;
#pragma unroll
    for (int kt = 0; kt < HIDDEN; kt += 32) {
        bf16x8 a = *(const bf16x8*)(xb + abase + kt);
#pragma unroll
        for (int t = 0; t < 8; ++t) {
            bf16x8 b = *(const bf16x8*)(wb + (size_t)(t * 16 + r) * HIDDEN + kt + ko);
            acc[t] = __builtin_amdgcn_mfma_f32_16x16x32_bf16(a, b, acc[t], 0, 0, 0);
        }
    }
    const int orow = row0 + (lane >> 4) * 4;
#pragma unroll
    for (int t = 0; t < 8; ++t) {
#pragma unroll
        for (int j = 0; j < 4; ++j) {
            int rr = orow + j;
            if (rr < N_NODES) hb[(size_t)rr * HIDDEN + t * 16 + r] = f2b(acc[t][j]);
        }
    }
}

// ---------------- degree + histogram ----------------
__global__ void deg_init(float* __restrict__ deg) {
    int n = blockIdx.x * blockDim.x + threadIdx.x;
    if (n < N_NODES) deg[n] = 1.0f;   // self-loop weight
}

__global__ void edge_hist(const int* __restrict__ dst, const float* __restrict__ w,
                          int* __restrict__ cnt, float* __restrict__ deg) {
    int e = blockIdx.x * blockDim.x + threadIdx.x;
    if (e >= N_EDGES) return;
    int d = dst[e];
    atomicAdd(&cnt[d], 1);
    atomicAdd(&deg[d], w[e]);
}

__global__ void deg_rsqrt(float* __restrict__ deg) {
    int n = blockIdx.x * blockDim.x + threadIdx.x;
    if (n < N_NODES) deg[n] = rsqrtf(deg[n]);
}

// ---------------- exclusive scan of cnt -> rowstart ----------------
__global__ void scan_partial(const int* __restrict__ cnt, int* __restrict__ bsum) {
    __shared__ int red[256];
    int i = blockIdx.x * 256 + threadIdx.x;
    red[threadIdx.x] = (i < N_NODES) ? cnt[i] : 0;
    __syncthreads();
    for (int off = 128; off > 0; off >>= 1) {
        if (threadIdx.x < off) red[threadIdx.x] += red[threadIdx.x + off];
        __syncthreads();
    }
    if (threadIdx.x == 0) bsum[blockIdx.x] = red[0];
}

__global__ void scan_bsums(const int* __restrict__ bsum, int* __restrict__ boff, int nblocks) {
    __shared__ int s[256];
    int t = threadIdx.x;
    int v0 = (t < nblocks) ? bsum[t] : 0;
    s[t] = v0;
    __syncthreads();
    for (int off = 1; off < 256; off <<= 1) {
        int v = (t >= off) ? s[t - off] : 0;
        __syncthreads();
        s[t] += v;
        __syncthreads();
    }
    boff[t] = s[t] - v0;   // exclusive
}

__global__ void scan_emit(const int* __restrict__ cnt, const int* __restrict__ boff,
                          int* __restrict__ rowstart) {
    __shared__ int s[256];
    int t = threadIdx.x;
    int i = blockIdx.x * 256 + t;
    int v0 = (i < N_NODES) ? cnt[i] : 0;
    s[t] = v0;
    __syncthreads();
    for (int off = 1; off < 256; off <<= 1) {
        int v = (t >= off) ? s[t - off] : 0;
        __syncthreads();
        s[t] += v;
        __syncthreads();
    }
    if (i < N_NODES) rowstart[i] = boff[blockIdx.x] + s[t] - v0;
    if (i == N_NODES) rowstart[N_NODES] = N_EDGES;
}

// ---------------- fill CSR ----------------
__global__ void csr_fill(const int* __restrict__ src, const int* __restrict__ dst,
                         const float* __restrict__ w, const float* __restrict__ dinv,
                         const int* __restrict__ rowstart, int* __restrict__ cnt,
                         int* __restrict__ esrc, float* __restrict__ enorm) {
    int e = blockIdx.x * blockDim.x + threadIdx.x;
    if (e >= N_EDGES) return;
    int s = src[e], d = dst[e];
    int r = atomicSub(&cnt[d], 1) - 1;
    int pos = rowstart[d] + r;
    esrc[pos]  = s;
    enorm[pos] = dinv[s] * w[e] * dinv[d];
}

// ---------------- gather (bf16 h) ----------------
__global__ __launch_bounds__(256) void gather_fused(const unsigned short* __restrict__ hb,
                                                    const int* __restrict__ rowstart,
                                                    const int* __restrict__ esrc,
                                                    const float* __restrict__ enorm,
                                                    const float* __restrict__ dinv,
                                                    const float* __restrict__ b,
                                                    float* __restrict__ out) {
    const int t = threadIdx.x;
    const int n = blockIdx.x * 8 + (t >> 5);
    if (n >= N_NODES) return;
    const int c4 = (t & 31) * 4;
    const int s0 = rowstart[n];
    const int e0 = rowstart[n + 1];
    const float di = dinv[n];
    const float sl = di * di;
    u16x4 hv = *(const u16x4*)(hb + (size_t)n * HIDDEN + c4);
    float4 acc;
    acc.x = sl * b2f(hv[0]); acc.y = sl * b2f(hv[1]);
    acc.z = sl * b2f(hv[2]); acc.w = sl * b2f(hv[3]);
    for (int p = s0; p < e0; ++p) {
        int s = esrc[p];
        float nm = enorm[p];
        u16x4 v = *(const u16x4*)(hb + (size_t)s * HIDDEN + c4);
        acc.x = fmaf(nm, b2f(v[0]), acc.x);
        acc.y = fmaf(nm, b2f(v[1]), acc.y);
        acc.z = fmaf(nm, b2f(v[2]), acc.z);
        acc.w = fmaf(nm, b2f(v[3]), acc.w);
    }
    float4 bv = *(const float4*)(b + c4);
    acc.x += bv.x; acc.y += bv.y; acc.z += bv.z; acc.w += bv.w;
    *(float4*)(out + (size_t)n * HIDDEN + c4) = acc;
}

// ---------------- graph boundaries ----------------
__global__ void bounds_init(int* __restrict__ gstart) {
    int g = threadIdx.x;
    if (g <= NUM_GRAPHS) gstart[g] = N_NODES;
}

__global__ void bounds_mark(const int* __restrict__ batch, int* __restrict__ gstart) {
    int n = blockIdx.x * blockDim.x + threadIdx.x;
    if (n >= N_NODES) return;
    int b0 = batch[n];
    int prev = (n == 0) ? -1 : batch[n - 1];
    for (int g = prev + 1; g <= b0; ++g) gstart[g] = n;
}

// ---------------- per-graph stats -> scale/shift ----------------
__global__ __launch_bounds__(256) void graph_stats(const float* __restrict__ out,
                                                   const int* __restrict__ gstart,
                                                   const float* __restrict__ ms,
                                                   const float* __restrict__ gw,
                                                   const float* __restrict__ gb,
                                                   float* __restrict__ scale,
                                                   float* __restrict__ shift) {
    const int g = blockIdx.x >> 2;
    const int q = blockIdx.x & 3;
    const int c = q * 32 + (threadIdx.x & 31);
    const int r = threadIdx.x >> 5;
    const int s = gstart[g];
    const int e = gstart[g + 1];
    float sum = 0.f, sq = 0.f;
    for (int n = s + r; n < e; n += 8) {
        float v = out[(size_t)n * HIDDEN + c];
        sum += v;
        sq = fmaf(v, v, sq);
    }
    __shared__ float ssum[8][32], ssq[8][32];
    ssum[r][threadIdx.x & 31] = sum;
    ssq[r][threadIdx.x & 31]  = sq;
    __syncthreads();
    if (r == 0) {
        int l = threadIdx.x & 31;
#pragma unroll
        for (int i = 1; i < 8; ++i) { sum += ssum[i][l]; sq += ssq[i][l]; }
        float cnt  = (float)max(e - s, 1);
        float mean = sum / cnt;
        float m2   = sq / cnt;
        float msv  = ms[c];
        float var  = fmaxf(m2 - mean * mean * msv * (2.f - msv), 0.f);
        float a    = gw[c] * rsqrtf(var + EPS_GN);
        scale[g * HIDDEN + c] = a;
        shift[g * HIDDEN + c] = gb[c] - a * msv * mean;
    }
}

// ---------------- normalize + affine + relu ----------------
__global__ __launch_bounds__(256) void gn_final(float* __restrict__ out,
                                                const float* __restrict__ scale,
                                                const float* __restrict__ shift,
                                                const int* __restrict__ batch) {
    int idx = blockIdx.x * blockDim.x + threadIdx.x;
    if (idx >= N_NODES * 32) return;
    int n  = idx >> 5;
    int c4 = (idx & 31) * 4;
    int g  = batch[n];
    float4 v  = *(float4*)(out + (size_t)n * HIDDEN + c4);
    float4 a  = *(const float4*)(scale + (size_t)g * HIDDEN + c4);
    float4 s  = *(const float4*)(shift + (size_t)g * HIDDEN + c4);
    v.x = fmaxf(fmaf(a.x, v.x, s.x), 0.f);
    v.y = fmaxf(fmaf(a.y, v.y, s.y), 0.f);
    v.z = fmaxf(fmaf(a.z, v.z, s.z), 0.f);
    v.w = fmaxf(fmaf(a.w, v.w, s.w), 0.f);
    *(float4*)(out + (size_t)n * HIDDEN + c4) = v;
}

extern "C" void kernel_launch(void* const* d_in, const int* in_sizes, int n_in,
                              void* d_out, int out_size, void* d_ws, size_t ws_size,
                              hipStream_t stream) {
    const float* node  = (const float*)d_in[0];
    const int*   ei    = (const int*)d_in[1];
    const float* eattr = (const float*)d_in[2];
    const int*   batch = (const int*)d_in[3];
    const float* W     = (const float*)d_in[4];
    const float* b     = (const float*)d_in[5];
    const float* gnw   = (const float*)d_in[6];
    const float* gnb   = (const float*)d_in[7];
    const float* gnms  = (const float*)d_in[8];
    float* out = (float*)d_out;
    float* ws  = (float*)d_ws;

    const int* src = ei;
    const int* dst = ei + N_EDGES;

    unsigned short* xb = (unsigned short*)(ws + XB_OFF);
    unsigned short* hb = (unsigned short*)(ws + HB_OFF);
    unsigned short* wb = (unsigned short*)(ws + WB_OFF);
    float* deg     = ws + DEG_OFF;
    float* scale   = ws + SCALE_OFF;
    float* shift   = ws + SHIFT_OFF;
    int*   gstart  = (int*)(ws + GSTART_OFF);
    int*   rowstart= (int*)(ws + ROWS_OFF);
    int*   cnt     = (int*)(ws + CNT_OFF);
    int*   bsum    = (int*)(ws + BSUM_OFF);
    int*   boff    = (int*)(ws + BOFF_OFF);
    int*   esrc    = (int*)(ws + ESRC_OFF);
    float* enorm   = ws + ENORM_OFF;

    const int NB = (N_NODES + 255) / 256;   // 196

    hipMemsetAsync(cnt, 0, (size_t)N_NODES * sizeof(int), stream);
    deg_init<<<NB, 256, 0, stream>>>(deg);
    cvt_f32_bf16<<<(HIDDEN * HIDDEN / 8 + 255) / 256, 256, 0, stream>>>(W, wb, HIDDEN * HIDDEN / 8);
    cvt_f32_bf16<<<(N_NODES * HIDDEN / 8 + 255) / 256, 256, 0, stream>>>(node, xb, N_NODES * HIDDEN / 8);
    gemm_mfma<<<(N_NODES + 63) / 64, 256, 0, stream>>>(xb, wb, hb);
    edge_hist<<<(N_EDGES + 255) / 256, 256, 0, stream>>>(dst, eattr, cnt, deg);
    deg_rsqrt<<<NB, 256, 0, stream>>>(deg);
    scan_partial<<<NB, 256, 0, stream>>>(cnt, bsum);
    scan_bsums<<<1, 256, 0, stream>>>(bsum, boff, NB);
    scan_emit<<<NB, 256, 0, stream>>>(cnt, boff, rowstart);
    csr_fill<<<(N_EDGES + 255) / 256, 256, 0, stream>>>(src, dst, eattr, deg, rowstart, cnt, esrc, enorm);
    gather_fused<<<(N_NODES + 7) / 8, 256, 0, stream>>>(hb, rowstart, esrc, enorm, deg, b, out);
    bounds_init<<<1, NUM_GRAPHS + 1, 0, stream>>>(gstart);
    bounds_mark<<<NB, 256, 0, stream>>>(batch, gstart);
    graph_stats<<<NUM_GRAPHS * 4, 256, 0, stream>>>(out, gstart, gnms, gnw, gnb, scale, shift);
    gn_final<<<(N_NODES * 32 + 255) / 256, 256, 0, stream>>>(out, scale, shift, batch);

    (void)in_sizes; (void)n_in; (void)out_size; (void)ws_size;
}

// Round 5
// 180.299 us; speedup vs baseline: 4.1879x; 1.2137x over previous
//
#include <hip/hip_runtime.h>

#define N_NODES    50000
#define N_EDGES    625000
#define HIDDEN     128
#define NUM_GRAPHS 128
#define EPS_GN     1e-5f
#define FIXSCALE   1048576.0f   // 2^20 fixed point for degree accumulation

typedef __bf16 bf16x8 __attribute__((ext_vector_type(8)));
typedef float  f32x4  __attribute__((ext_vector_type(4)));
typedef unsigned short u16x4 __attribute__((ext_vector_type(4)));
typedef unsigned long long u64;

__device__ inline unsigned short f2b(float f) {
    __bf16 b = (__bf16)f;
    return __builtin_bit_cast(unsigned short, b);
}
__device__ inline float b2f(unsigned short u) {
    unsigned int x = ((unsigned int)u) << 16;
    return __builtin_bit_cast(float, x);
}

// ---- workspace layout (4B units; u64 regions at even offsets) ----
#define HB_OFF     0          // ushort[6,400,000]  bf16(h)        -> 3,200,000 units
#define CNT64_OFF  3200000    // u64[50,000]                       -> 100,000 units
#define DINV_OFF   3300000    // float[50,000]
#define SCALE_OFF  3350000    // float[16,384]
#define SHIFT_OFF  3366384    // float[16,384]
#define GSTART_OFF 3382768    // int[129]
#define ROWS_OFF   3383000    // int[50,001]
#define BSUM_OFF   3433100    // int[256]
#define BOFF_OFF   3433400    // int[256]
#define EPACK_OFF  3433700    // u64[625,000]                      -> 1,250,000 units (even offset)
// end 4,683,700 * 4B = 18.7 MB

// ---------------- MFMA GEMM: h = x @ W.T, f32 in (cvt in-reg), bf16 out ----------------
__global__ __launch_bounds__(256) void gemm_mfma(const float* __restrict__ x,
                                                 const float* __restrict__ W,
                                                 unsigned short* __restrict__ hb) {
    const int wave = threadIdx.x >> 6;
    const int lane = threadIdx.x & 63;
    const int row0 = blockIdx.x * 64 + wave * 16;
    const int r  = lane & 15;          // A row / B col within tile
    const int ko = (lane >> 4) * 8;    // k offset within 32-wide k-step
    f32x4 acc[8];
#pragma unroll
    for (int t = 0; t < 8; ++t) { acc[t][0] = 0.f; acc[t][1] = 0.f; acc[t][2] = 0.f; acc[t][3] = 0.f; }
    int arow = row0 + r;
    if (arow >= N_NODES) arow = N_NODES - 1;   // clamp; stores are bounds-checked
    const size_t abase = (size_t)arow * HIDDEN + ko;
#pragma unroll
    for (int kt = 0; kt < HIDDEN; kt += 32) {
        float4 a0 = *(const float4*)(x + abase + kt);
        float4 a1 = *(const float4*)(x + abase + kt + 4);
        bf16x8 a;
        a[0] = (__bf16)a0.x; a[1] = (__bf16)a0.y; a[2] = (__bf16)a0.z; a[3] = (__bf16)a0.w;
        a[4] = (__bf16)a1.x; a[5] = (__bf16)a1.y; a[6] = (__bf16)a1.z; a[7] = (__bf16)a1.w;
#pragma unroll
        for (int t = 0; t < 8; ++t) {
            const float* wp = W + (size_t)(t * 16 + r) * HIDDEN + kt + ko;
            float4 b0 = *(const float4*)(wp);
            float4 b1 = *(const float4*)(wp + 4);
            bf16x8 b;
            b[0] = (__bf16)b0.x; b[1] = (__bf16)b0.y; b[2] = (__bf16)b0.z; b[3] = (__bf16)b0.w;
            b[4] = (__bf16)b1.x; b[5] = (__bf16)b1.y; b[6] = (__bf16)b1.z; b[7] = (__bf16)b1.w;
            acc[t] = __builtin_amdgcn_mfma_f32_16x16x32_bf16(a, b, acc[t], 0, 0, 0);
        }
    }
    const int orow = row0 + (lane >> 4) * 4;
#pragma unroll
    for (int t = 0; t < 8; ++t) {
#pragma unroll
        for (int j = 0; j < 4; ++j) {
            int rr = orow + j;
            if (rr < N_NODES) hb[(size_t)rr * HIDDEN + t * 16 + r] = f2b(acc[t][j]);
        }
    }
}

// ---------------- packed histogram: cnt64[d] += (1<<32) | fix20(w) ----------------
__global__ void edge_hist(const int* __restrict__ dst, const float* __restrict__ w,
                          u64* __restrict__ cnt64) {
    int e = blockIdx.x * blockDim.x + threadIdx.x;
    if (e >= N_EDGES) return;
    int d = dst[e];
    unsigned int fx = (unsigned int)(w[e] * FIXSCALE + 0.5f);
    atomicAdd(&cnt64[d], (1ULL << 32) | (u64)fx);
}

// ---------------- scan partial sums + dinv = rsqrt(1 + deg) ----------------
__global__ void scan_partial(const u64* __restrict__ cnt64, int* __restrict__ bsum,
                             float* __restrict__ dinv) {
    __shared__ int red[256];
    int i = blockIdx.x * 256 + threadIdx.x;
    int c = 0;
    if (i < N_NODES) {
        u64 v = cnt64[i];
        c = (int)(v >> 32);
        dinv[i] = rsqrtf(1.0f + (float)(unsigned int)v * (1.0f / FIXSCALE));
    }
    red[threadIdx.x] = c;
    __syncthreads();
    for (int off = 128; off > 0; off >>= 1) {
        if (threadIdx.x < off) red[threadIdx.x] += red[threadIdx.x + off];
        __syncthreads();
    }
    if (threadIdx.x == 0) bsum[blockIdx.x] = red[0];
}

__global__ void scan_bsums(const int* __restrict__ bsum, int* __restrict__ boff, int nblocks) {
    __shared__ int s[256];
    int t = threadIdx.x;
    int v0 = (t < nblocks) ? bsum[t] : 0;
    s[t] = v0;
    __syncthreads();
    for (int off = 1; off < 256; off <<= 1) {
        int v = (t >= off) ? s[t - off] : 0;
        __syncthreads();
        s[t] += v;
        __syncthreads();
    }
    boff[t] = s[t] - v0;   // exclusive
}

__global__ void scan_emit(const u64* __restrict__ cnt64, const int* __restrict__ boff,
                          int* __restrict__ rowstart) {
    __shared__ int s[256];
    int t = threadIdx.x;
    int i = blockIdx.x * 256 + t;
    int v0 = (i < N_NODES) ? (int)(cnt64[i] >> 32) : 0;
    s[t] = v0;
    __syncthreads();
    for (int off = 1; off < 256; off <<= 1) {
        int v = (t >= off) ? s[t - off] : 0;
        __syncthreads();
        s[t] += v;
        __syncthreads();
    }
    if (i < N_NODES) rowstart[i] = boff[blockIdx.x] + s[t] - v0;
    if (i == N_NODES) rowstart[N_NODES] = N_EDGES;
}

// ---------------- fill CSR: packed (src | norm) u64, hi32 countdown ----------------
__global__ void csr_fill(const int* __restrict__ src, const int* __restrict__ dst,
                         const float* __restrict__ w, const float* __restrict__ dinv,
                         const int* __restrict__ rowstart, u64* __restrict__ cnt64,
                         u64* __restrict__ epack) {
    int e = blockIdx.x * blockDim.x + threadIdx.x;
    if (e >= N_EDGES) return;
    int s = src[e], d = dst[e];
    u64 old = atomicAdd(&cnt64[d], 0xFFFFFFFF00000000ULL);   // hi32 -= 1
    int r = (int)(old >> 32) - 1;
    int pos = rowstart[d] + r;
    float nm = dinv[s] * w[e] * dinv[d];
    epack[pos] = (u64)(unsigned int)s | ((u64)__float_as_uint(nm) << 32);
}

// ---------------- gather (bf16 h, packed edges) ----------------
__global__ __launch_bounds__(256) void gather_fused(const unsigned short* __restrict__ hb,
                                                    const int* __restrict__ rowstart,
                                                    const u64* __restrict__ epack,
                                                    const float* __restrict__ dinv,
                                                    const float* __restrict__ b,
                                                    float* __restrict__ out) {
    const int t = threadIdx.x;
    const int n = blockIdx.x * 8 + (t >> 5);
    if (n >= N_NODES) return;
    const int c4 = (t & 31) * 4;
    const int s0 = rowstart[n];
    const int e0 = rowstart[n + 1];
    const float di = dinv[n];
    const float sl = di * di;
    u16x4 hv = *(const u16x4*)(hb + (size_t)n * HIDDEN + c4);
    float4 acc;
    acc.x = sl * b2f(hv[0]); acc.y = sl * b2f(hv[1]);
    acc.z = sl * b2f(hv[2]); acc.w = sl * b2f(hv[3]);
    int p = s0;
    for (; p + 2 <= e0; p += 2) {
        u64 e1 = epack[p];
        u64 e2 = epack[p + 1];
        int   s1 = (int)(unsigned int)e1;
        float n1 = __uint_as_float((unsigned int)(e1 >> 32));
        int   s2 = (int)(unsigned int)e2;
        float n2 = __uint_as_float((unsigned int)(e2 >> 32));
        u16x4 v1 = *(const u16x4*)(hb + (size_t)s1 * HIDDEN + c4);
        u16x4 v2 = *(const u16x4*)(hb + (size_t)s2 * HIDDEN + c4);
        acc.x = fmaf(n1, b2f(v1[0]), acc.x);
        acc.y = fmaf(n1, b2f(v1[1]), acc.y);
        acc.z = fmaf(n1, b2f(v1[2]), acc.z);
        acc.w = fmaf(n1, b2f(v1[3]), acc.w);
        acc.x = fmaf(n2, b2f(v2[0]), acc.x);
        acc.y = fmaf(n2, b2f(v2[1]), acc.y);
        acc.z = fmaf(n2, b2f(v2[2]), acc.z);
        acc.w = fmaf(n2, b2f(v2[3]), acc.w);
    }
    if (p < e0) {
        u64 e1 = epack[p];
        int   s1 = (int)(unsigned int)e1;
        float n1 = __uint_as_float((unsigned int)(e1 >> 32));
        u16x4 v1 = *(const u16x4*)(hb + (size_t)s1 * HIDDEN + c4);
        acc.x = fmaf(n1, b2f(v1[0]), acc.x);
        acc.y = fmaf(n1, b2f(v1[1]), acc.y);
        acc.z = fmaf(n1, b2f(v1[2]), acc.z);
        acc.w = fmaf(n1, b2f(v1[3]), acc.w);
    }
    float4 bv = *(const float4*)(b + c4);
    acc.x += bv.x; acc.y += bv.y; acc.z += bv.z; acc.w += bv.w;
    *(float4*)(out + (size_t)n * HIDDEN + c4) = acc;
}

// ---------------- graph boundaries ----------------
__global__ void bounds_init(int* __restrict__ gstart) {
    int g = threadIdx.x;
    if (g <= NUM_GRAPHS) gstart[g] = N_NODES;
}

__global__ void bounds_mark(const int* __restrict__ batch, int* __restrict__ gstart) {
    int n = blockIdx.x * blockDim.x + threadIdx.x;
    if (n >= N_NODES) return;
    int b0 = batch[n];
    int prev = (n == 0) ? -1 : batch[n - 1];
    for (int g = prev + 1; g <= b0; ++g) gstart[g] = n;
}

// ---------------- per-graph stats -> scale/shift ----------------
__global__ __launch_bounds__(256) void graph_stats(const float* __restrict__ out,
                                                   const int* __restrict__ gstart,
                                                   const float* __restrict__ ms,
                                                   const float* __restrict__ gw,
                                                   const float* __restrict__ gb,
                                                   float* __restrict__ scale,
                                                   float* __restrict__ shift) {
    const int g = blockIdx.x >> 2;
    const int q = blockIdx.x & 3;
    const int c = q * 32 + (threadIdx.x & 31);
    const int r = threadIdx.x >> 5;
    const int s = gstart[g];
    const int e = gstart[g + 1];
    float sum = 0.f, sq = 0.f;
    for (int n = s + r; n < e; n += 8) {
        float v = out[(size_t)n * HIDDEN + c];
        sum += v;
        sq = fmaf(v, v, sq);
    }
    __shared__ float ssum[8][32], ssq[8][32];
    ssum[r][threadIdx.x & 31] = sum;
    ssq[r][threadIdx.x & 31]  = sq;
    __syncthreads();
    if (r == 0) {
        int l = threadIdx.x & 31;
#pragma unroll
        for (int i = 1; i < 8; ++i) { sum += ssum[i][l]; sq += ssq[i][l]; }
        float cnt  = (float)max(e - s, 1);
        float mean = sum / cnt;
        float m2   = sq / cnt;
        float msv  = ms[c];
        float var  = fmaxf(m2 - mean * mean * msv * (2.f - msv), 0.f);
        float a    = gw[c] * rsqrtf(var + EPS_GN);
        scale[g * HIDDEN + c] = a;
        shift[g * HIDDEN + c] = gb[c] - a * msv * mean;
    }
}

// ---------------- normalize + affine + relu ----------------
__global__ __launch_bounds__(256) void gn_final(float* __restrict__ out,
                                                const float* __restrict__ scale,
                                                const float* __restrict__ shift,
                                                const int* __restrict__ batch) {
    int idx = blockIdx.x * blockDim.x + threadIdx.x;
    if (idx >= N_NODES * 32) return;
    int n  = idx >> 5;
    int c4 = (idx & 31) * 4;
    int g  = batch[n];
    float4 v  = *(float4*)(out + (size_t)n * HIDDEN + c4);
    float4 a  = *(const float4*)(scale + (size_t)g * HIDDEN + c4);
    float4 s  = *(const float4*)(shift + (size_t)g * HIDDEN + c4);
    v.x = fmaxf(fmaf(a.x, v.x, s.x), 0.f);
    v.y = fmaxf(fmaf(a.y, v.y, s.y), 0.f);
    v.z = fmaxf(fmaf(a.z, v.z, s.z), 0.f);
    v.w = fmaxf(fmaf(a.w, v.w, s.w), 0.f);
    *(float4*)(out + (size_t)n * HIDDEN + c4) = v;
}

extern "C" void kernel_launch(void* const* d_in, const int* in_sizes, int n_in,
                              void* d_out, int out_size, void* d_ws, size_t ws_size,
                              hipStream_t stream) {
    const float* node  = (const float*)d_in[0];
    const int*   ei    = (const int*)d_in[1];
    const float* eattr = (const float*)d_in[2];
    const int*   batch = (const int*)d_in[3];
    const float* W     = (const float*)d_in[4];
    const float* b     = (const float*)d_in[5];
    const float* gnw   = (const float*)d_in[6];
    const float* gnb   = (const float*)d_in[7];
    const float* gnms  = (const float*)d_in[8];
    float* out = (float*)d_out;
    float* ws  = (float*)d_ws;

    const int* src = ei;
    const int* dst = ei + N_EDGES;

    unsigned short* hb = (unsigned short*)(ws + HB_OFF);
    u64*   cnt64   = (u64*)(ws + CNT64_OFF);
    float* dinv    = ws + DINV_OFF;
    float* scale   = ws + SCALE_OFF;
    float* shift   = ws + SHIFT_OFF;
    int*   gstart  = (int*)(ws + GSTART_OFF);
    int*   rowstart= (int*)(ws + ROWS_OFF);
    int*   bsum    = (int*)(ws + BSUM_OFF);
    int*   boff    = (int*)(ws + BOFF_OFF);
    u64*   epack   = (u64*)(ws + EPACK_OFF);

    const int NB = (N_NODES + 255) / 256;   // 196

    hipMemsetAsync(cnt64, 0, (size_t)N_NODES * sizeof(u64), stream);
    gemm_mfma<<<(N_NODES + 63) / 64, 256, 0, stream>>>(node, W, hb);
    edge_hist<<<(N_EDGES + 255) / 256, 256, 0, stream>>>(dst, eattr, cnt64);
    scan_partial<<<NB, 256, 0, stream>>>(cnt64, bsum, dinv);
    scan_bsums<<<1, 256, 0, stream>>>(bsum, boff, NB);
    scan_emit<<<NB, 256, 0, stream>>>(cnt64, boff, rowstart);
    csr_fill<<<(N_EDGES + 255) / 256, 256, 0, stream>>>(src, dst, eattr, dinv, rowstart, cnt64, epack);
    gather_fused<<<(N_NODES + 7) / 8, 256, 0, stream>>>(hb, rowstart, epack, dinv, b, out);
    bounds_init<<<1, NUM_GRAPHS + 1, 0, stream>>>(gstart);
    bounds_mark<<<NB, 256, 0, stream>>>(batch, gstart);
    graph_stats<<<NUM_GRAPHS * 4, 256, 0, stream>>>(out, gstart, gnms, gnw, gnb, scale, shift);
    gn_final<<<(N_NODES * 32 + 255) / 256, 256, 0, stream>>>(out, scale, shift, batch);

    (void)in_sizes; (void)n_in; (void)out_size; (void)ws_size;
}

// Round 6
// 172.314 us; speedup vs baseline: 4.3819x; 1.0463x over previous
//
#include <hip/hip_runtime.h>

#define N_NODES    50000
#define N_EDGES    625000
#define HIDDEN     128
#define NUM_GRAPHS 128
#define EPS_GN     1e-5f
#define FIXSCALE   1048576.0f   // 2^20 fixed point for degree accumulation

typedef __bf16 bf16x8 __attribute__((ext_vector_type(8)));
typedef float  f32x4  __attribute__((ext_vector_type(4)));
typedef unsigned short u16x4 __attribute__((ext_vector_type(4)));
typedef unsigned long long u64;

__device__ inline unsigned short f2b(float f) {
    __bf16 b = (__bf16)f;
    return __builtin_bit_cast(unsigned short, b);
}
__device__ inline float b2f(unsigned short u) {
    unsigned int x = ((unsigned int)u) << 16;
    return __builtin_bit_cast(float, x);
}

// ---- workspace layout (4B units; u64 regions at even offsets) ----
#define HB_OFF     0          // ushort[6,400,000]  bf16(h)        -> 3,200,000 units
#define CNT64_OFF  3200000    // u64[50,000]                       -> 100,000 units
#define DINV_OFF   3300000    // float[50,000]
#define SCALE_OFF  3350000    // float[16,384]
#define SHIFT_OFF  3366384    // float[16,384]
#define GSTART_OFF 3382768    // int[129]
#define ROWS_OFF   3383000    // int[50,001]
#define BSUM_OFF   3433100    // int[256]
#define BOFF_OFF   3433400    // int[256]
#define EPACK_OFF  3433700    // u64[625,000]                      -> 1,250,000 units (even offset)
// end 4,683,700 * 4B = 18.7 MB

// ---------------- MFMA GEMM: h = x @ W.T; prologue zeroes cnt64 ----------------
__global__ __launch_bounds__(256) void gemm_mfma(const float* __restrict__ x,
                                                 const float* __restrict__ W,
                                                 unsigned short* __restrict__ hb,
                                                 unsigned int* __restrict__ cnt_zero) {
    // zero cnt64 region (100,000 u32 words); grid is 782*256 = 200,192 threads
    {
        int zi = blockIdx.x * 256 + threadIdx.x;
        if (zi < 2 * N_NODES) cnt_zero[zi] = 0u;
    }
    const int wave = threadIdx.x >> 6;
    const int lane = threadIdx.x & 63;
    const int row0 = blockIdx.x * 64 + wave * 16;
    const int r  = lane & 15;          // A row / B col within tile
    const int ko = (lane >> 4) * 8;    // k offset within 32-wide k-step
    f32x4 acc[8];
#pragma unroll
    for (int t = 0; t < 8; ++t) { acc[t][0] = 0.f; acc[t][1] = 0.f; acc[t][2] = 0.f; acc[t][3] = 0.f; }
    int arow = row0 + r;
    if (arow >= N_NODES) arow = N_NODES - 1;   // clamp; stores are bounds-checked
    const size_t abase = (size_t)arow * HIDDEN + ko;
#pragma unroll
    for (int kt = 0; kt < HIDDEN; kt += 32) {
        float4 a0 = *(const float4*)(x + abase + kt);
        float4 a1 = *(const float4*)(x + abase + kt + 4);
        bf16x8 a;
        a[0] = (__bf16)a0.x; a[1] = (__bf16)a0.y; a[2] = (__bf16)a0.z; a[3] = (__bf16)a0.w;
        a[4] = (__bf16)a1.x; a[5] = (__bf16)a1.y; a[6] = (__bf16)a1.z; a[7] = (__bf16)a1.w;
#pragma unroll
        for (int t = 0; t < 8; ++t) {
            const float* wp = W + (size_t)(t * 16 + r) * HIDDEN + kt + ko;
            float4 b0 = *(const float4*)(wp);
            float4 b1 = *(const float4*)(wp + 4);
            bf16x8 b;
            b[0] = (__bf16)b0.x; b[1] = (__bf16)b0.y; b[2] = (__bf16)b0.z; b[3] = (__bf16)b0.w;
            b[4] = (__bf16)b1.x; b[5] = (__bf16)b1.y; b[6] = (__bf16)b1.z; b[7] = (__bf16)b1.w;
            acc[t] = __builtin_amdgcn_mfma_f32_16x16x32_bf16(a, b, acc[t], 0, 0, 0);
        }
    }
    const int orow = row0 + (lane >> 4) * 4;
#pragma unroll
    for (int t = 0; t < 8; ++t) {
#pragma unroll
        for (int j = 0; j < 4; ++j) {
            int rr = orow + j;
            if (rr < N_NODES) hb[(size_t)rr * HIDDEN + t * 16 + r] = f2b(acc[t][j]);
        }
    }
}

// ---------------- packed histogram: cnt64[d] += (1<<32) | fix20(w) ----------------
__global__ void edge_hist(const int* __restrict__ dst, const float* __restrict__ w,
                          u64* __restrict__ cnt64) {
    int e = blockIdx.x * blockDim.x + threadIdx.x;
    if (e >= N_EDGES) return;
    int d = dst[e];
    unsigned int fx = (unsigned int)(w[e] * FIXSCALE + 0.5f);
    atomicAdd(&cnt64[d], (1ULL << 32) | (u64)fx);
}

// ---------------- scan partials + dinv + graph bounds (fused) ----------------
__global__ void scan_partial(const u64* __restrict__ cnt64, int* __restrict__ bsum,
                             float* __restrict__ dinv,
                             const int* __restrict__ batch, int* __restrict__ gstart) {
    __shared__ int red[256];
    int i = blockIdx.x * 256 + threadIdx.x;
    int c = 0;
    if (i < N_NODES) {
        u64 v = cnt64[i];
        c = (int)(v >> 32);
        dinv[i] = rsqrtf(1.0f + (float)(unsigned int)v * (1.0f / FIXSCALE));
        // graph boundary marking (batch is sorted)
        int b0 = batch[i];
        int prev = (i == 0) ? -1 : batch[i - 1];
        for (int g = prev + 1; g <= b0; ++g) gstart[g] = i;
        if (i == N_NODES - 1) {
            for (int g = b0 + 1; g <= NUM_GRAPHS; ++g) gstart[g] = N_NODES;
        }
    }
    red[threadIdx.x] = c;
    __syncthreads();
    for (int off = 128; off > 0; off >>= 1) {
        if (threadIdx.x < off) red[threadIdx.x] += red[threadIdx.x + off];
        __syncthreads();
    }
    if (threadIdx.x == 0) bsum[blockIdx.x] = red[0];
}

__global__ void scan_bsums(const int* __restrict__ bsum, int* __restrict__ boff, int nblocks) {
    __shared__ int s[256];
    int t = threadIdx.x;
    int v0 = (t < nblocks) ? bsum[t] : 0;
    s[t] = v0;
    __syncthreads();
    for (int off = 1; off < 256; off <<= 1) {
        int v = (t >= off) ? s[t - off] : 0;
        __syncthreads();
        s[t] += v;
        __syncthreads();
    }
    boff[t] = s[t] - v0;   // exclusive
}

__global__ void scan_emit(const u64* __restrict__ cnt64, const int* __restrict__ boff,
                          int* __restrict__ rowstart) {
    __shared__ int s[256];
    int t = threadIdx.x;
    int i = blockIdx.x * 256 + t;
    int v0 = (i < N_NODES) ? (int)(cnt64[i] >> 32) : 0;
    s[t] = v0;
    __syncthreads();
    for (int off = 1; off < 256; off <<= 1) {
        int v = (t >= off) ? s[t - off] : 0;
        __syncthreads();
        s[t] += v;
        __syncthreads();
    }
    if (i < N_NODES) rowstart[i] = boff[blockIdx.x] + s[t] - v0;
    if (i == N_NODES) rowstart[N_NODES] = N_EDGES;
}

// ---------------- fill CSR: packed (src | norm) u64, hi32 countdown ----------------
__global__ void csr_fill(const int* __restrict__ src, const int* __restrict__ dst,
                         const float* __restrict__ w, const float* __restrict__ dinv,
                         const int* __restrict__ rowstart, u64* __restrict__ cnt64,
                         u64* __restrict__ epack) {
    int e = blockIdx.x * blockDim.x + threadIdx.x;
    if (e >= N_EDGES) return;
    int s = src[e], d = dst[e];
    u64 old = atomicAdd(&cnt64[d], 0xFFFFFFFF00000000ULL);   // hi32 -= 1
    int r = (int)(old >> 32) - 1;
    int pos = rowstart[d] + r;
    float nm = dinv[s] * w[e] * dinv[d];
    epack[pos] = (u64)(unsigned int)s | ((u64)__float_as_uint(nm) << 32);
}

// ---------------- gather (bf16 h, packed edges) ----------------
__global__ __launch_bounds__(256) void gather_fused(const unsigned short* __restrict__ hb,
                                                    const int* __restrict__ rowstart,
                                                    const u64* __restrict__ epack,
                                                    const float* __restrict__ dinv,
                                                    const float* __restrict__ b,
                                                    float* __restrict__ out) {
    const int t = threadIdx.x;
    const int n = blockIdx.x * 8 + (t >> 5);
    if (n >= N_NODES) return;
    const int c4 = (t & 31) * 4;
    const int s0 = rowstart[n];
    const int e0 = rowstart[n + 1];
    const float di = dinv[n];
    const float sl = di * di;
    u16x4 hv = *(const u16x4*)(hb + (size_t)n * HIDDEN + c4);
    float4 acc;
    acc.x = sl * b2f(hv[0]); acc.y = sl * b2f(hv[1]);
    acc.z = sl * b2f(hv[2]); acc.w = sl * b2f(hv[3]);
    int p = s0;
    for (; p + 2 <= e0; p += 2) {
        u64 e1 = epack[p];
        u64 e2 = epack[p + 1];
        int   s1 = (int)(unsigned int)e1;
        float n1 = __uint_as_float((unsigned int)(e1 >> 32));
        int   s2 = (int)(unsigned int)e2;
        float n2 = __uint_as_float((unsigned int)(e2 >> 32));
        u16x4 v1 = *(const u16x4*)(hb + (size_t)s1 * HIDDEN + c4);
        u16x4 v2 = *(const u16x4*)(hb + (size_t)s2 * HIDDEN + c4);
        acc.x = fmaf(n1, b2f(v1[0]), acc.x);
        acc.y = fmaf(n1, b2f(v1[1]), acc.y);
        acc.z = fmaf(n1, b2f(v1[2]), acc.z);
        acc.w = fmaf(n1, b2f(v1[3]), acc.w);
        acc.x = fmaf(n2, b2f(v2[0]), acc.x);
        acc.y = fmaf(n2, b2f(v2[1]), acc.y);
        acc.z = fmaf(n2, b2f(v2[2]), acc.z);
        acc.w = fmaf(n2, b2f(v2[3]), acc.w);
    }
    if (p < e0) {
        u64 e1 = epack[p];
        int   s1 = (int)(unsigned int)e1;
        float n1 = __uint_as_float((unsigned int)(e1 >> 32));
        u16x4 v1 = *(const u16x4*)(hb + (size_t)s1 * HIDDEN + c4);
        acc.x = fmaf(n1, b2f(v1[0]), acc.x);
        acc.y = fmaf(n1, b2f(v1[1]), acc.y);
        acc.z = fmaf(n1, b2f(v1[2]), acc.z);
        acc.w = fmaf(n1, b2f(v1[3]), acc.w);
    }
    float4 bv = *(const float4*)(b + c4);
    acc.x += bv.x; acc.y += bv.y; acc.z += bv.z; acc.w += bv.w;
    *(float4*)(out + (size_t)n * HIDDEN + c4) = acc;
}

// ---------------- per-graph stats -> scale/shift ----------------
__global__ __launch_bounds__(256) void graph_stats(const float* __restrict__ out,
                                                   const int* __restrict__ gstart,
                                                   const float* __restrict__ ms,
                                                   const float* __restrict__ gw,
                                                   const float* __restrict__ gb,
                                                   float* __restrict__ scale,
                                                   float* __restrict__ shift) {
    const int g = blockIdx.x >> 2;
    const int q = blockIdx.x & 3;
    const int c = q * 32 + (threadIdx.x & 31);
    const int r = threadIdx.x >> 5;
    const int s = gstart[g];
    const int e = gstart[g + 1];
    float sum = 0.f, sq = 0.f;
    for (int n = s + r; n < e; n += 8) {
        float v = out[(size_t)n * HIDDEN + c];
        sum += v;
        sq = fmaf(v, v, sq);
    }
    __shared__ float ssum[8][32], ssq[8][32];
    ssum[r][threadIdx.x & 31] = sum;
    ssq[r][threadIdx.x & 31]  = sq;
    __syncthreads();
    if (r == 0) {
        int l = threadIdx.x & 31;
#pragma unroll
        for (int i = 1; i < 8; ++i) { sum += ssum[i][l]; sq += ssq[i][l]; }
        float cnt  = (float)max(e - s, 1);
        float mean = sum / cnt;
        float m2   = sq / cnt;
        float msv  = ms[c];
        float var  = fmaxf(m2 - mean * mean * msv * (2.f - msv), 0.f);
        float a    = gw[c] * rsqrtf(var + EPS_GN);
        scale[g * HIDDEN + c] = a;
        shift[g * HIDDEN + c] = gb[c] - a * msv * mean;
    }
}

// ---------------- normalize + affine + relu ----------------
__global__ __launch_bounds__(256) void gn_final(float* __restrict__ out,
                                                const float* __restrict__ scale,
                                                const float* __restrict__ shift,
                                                const int* __restrict__ batch) {
    int idx = blockIdx.x * blockDim.x + threadIdx.x;
    if (idx >= N_NODES * 32) return;
    int n  = idx >> 5;
    int c4 = (idx & 31) * 4;
    int g  = batch[n];
    float4 v  = *(float4*)(out + (size_t)n * HIDDEN + c4);
    float4 a  = *(const float4*)(scale + (size_t)g * HIDDEN + c4);
    float4 s  = *(const float4*)(shift + (size_t)g * HIDDEN + c4);
    v.x = fmaxf(fmaf(a.x, v.x, s.x), 0.f);
    v.y = fmaxf(fmaf(a.y, v.y, s.y), 0.f);
    v.z = fmaxf(fmaf(a.z, v.z, s.z), 0.f);
    v.w = fmaxf(fmaf(a.w, v.w, s.w), 0.f);
    *(float4*)(out + (size_t)n * HIDDEN + c4) = v;
}

extern "C" void kernel_launch(void* const* d_in, const int* in_sizes, int n_in,
                              void* d_out, int out_size, void* d_ws, size_t ws_size,
                              hipStream_t stream) {
    const float* node  = (const float*)d_in[0];
    const int*   ei    = (const int*)d_in[1];
    const float* eattr = (const float*)d_in[2];
    const int*   batch = (const int*)d_in[3];
    const float* W     = (const float*)d_in[4];
    const float* b     = (const float*)d_in[5];
    const float* gnw   = (const float*)d_in[6];
    const float* gnb   = (const float*)d_in[7];
    const float* gnms  = (const float*)d_in[8];
    float* out = (float*)d_out;
    float* ws  = (float*)d_ws;

    const int* src = ei;
    const int* dst = ei + N_EDGES;

    unsigned short* hb = (unsigned short*)(ws + HB_OFF);
    u64*   cnt64   = (u64*)(ws + CNT64_OFF);
    float* dinv    = ws + DINV_OFF;
    float* scale   = ws + SCALE_OFF;
    float* shift   = ws + SHIFT_OFF;
    int*   gstart  = (int*)(ws + GSTART_OFF);
    int*   rowstart= (int*)(ws + ROWS_OFF);
    int*   bsum    = (int*)(ws + BSUM_OFF);
    int*   boff    = (int*)(ws + BOFF_OFF);
    u64*   epack   = (u64*)(ws + EPACK_OFF);

    const int NB = (N_NODES + 255) / 256;   // 196

    gemm_mfma<<<(N_NODES + 63) / 64, 256, 0, stream>>>(node, W, hb, (unsigned int*)cnt64);
    edge_hist<<<(N_EDGES + 255) / 256, 256, 0, stream>>>(dst, eattr, cnt64);
    scan_partial<<<NB, 256, 0, stream>>>(cnt64, bsum, dinv, batch, gstart);
    scan_bsums<<<1, 256, 0, stream>>>(bsum, boff, NB);
    scan_emit<<<NB, 256, 0, stream>>>(cnt64, boff, rowstart);
    csr_fill<<<(N_EDGES + 255) / 256, 256, 0, stream>>>(src, dst, eattr, dinv, rowstart, cnt64, epack);
    gather_fused<<<(N_NODES + 7) / 8, 256, 0, stream>>>(hb, rowstart, epack, dinv, b, out);
    graph_stats<<<NUM_GRAPHS * 4, 256, 0, stream>>>(out, gstart, gnms, gnw, gnb, scale, shift);
    gn_final<<<(N_NODES * 32 + 255) / 256, 256, 0, stream>>>(out, scale, shift, batch);

    (void)in_sizes; (void)n_in; (void)out_size; (void)ws_size;
}

// Round 7
// 149.104 us; speedup vs baseline: 5.0640x; 1.1557x over previous
//
#include <hip/hip_runtime.h>

#define N_NODES    50000
#define N_EDGES    625000
#define HIDDEN     128
#define NUM_GRAPHS 128
#define EPS_GN     1e-5f
#define FIXSCALE   1048576.0f   // 2^20 fixed point for degree accumulation

typedef __bf16 bf16x8 __attribute__((ext_vector_type(8)));
typedef float  f32x4  __attribute__((ext_vector_type(4)));
typedef unsigned short u16x8 __attribute__((ext_vector_type(8)));
typedef unsigned long long u64;

__device__ inline unsigned short f2b(float f) {
    __bf16 b = (__bf16)f;
    return __builtin_bit_cast(unsigned short, b);
}
__device__ inline float b2f(unsigned short u) {
    unsigned int x = ((unsigned int)u) << 16;
    return __builtin_bit_cast(float, x);
}

// ---- workspace layout (4B units; u64 regions at even offsets) ----
#define HB_OFF     0          // ushort[6,400,000] bf16(h)  -> 3,200,000 units
#define CNT64_OFF  3200000    // u64[50,000]                -> 100,000 units
#define DINV_OFF   3300000    // float[50,000]
#define SCALE_OFF  3350000    // float[16,384]
#define SHIFT_OFF  3366384    // float[16,384]
#define GSTART_OFF 3382768    // int[129]
#define ROWS_OFF   3383000    // int[50,001]
#define BSUM_OFF   3433100    // int[256]
#define BOFF_OFF   3433400    // int[256]
#define EPACK_OFF  3433700    // u64[625,000]               -> 1,250,000 units (even)
#define SLOT_OFF   4683700    // u32[625,000]
// end 5,308,700 * 4B = 21.2 MB

// ---------------- MFMA GEMM: h = x @ W.T; prologue zeroes cnt64 ----------------
__global__ __launch_bounds__(256) void gemm_mfma(const float* __restrict__ x,
                                                 const float* __restrict__ W,
                                                 unsigned short* __restrict__ hb,
                                                 unsigned int* __restrict__ cnt_zero) {
    {
        int zi = blockIdx.x * 256 + threadIdx.x;
        if (zi < 2 * N_NODES) cnt_zero[zi] = 0u;
    }
    const int wave = threadIdx.x >> 6;
    const int lane = threadIdx.x & 63;
    const int row0 = blockIdx.x * 64 + wave * 16;
    const int r  = lane & 15;
    const int ko = (lane >> 4) * 8;
    f32x4 acc[8];
#pragma unroll
    for (int t = 0; t < 8; ++t) { acc[t][0] = 0.f; acc[t][1] = 0.f; acc[t][2] = 0.f; acc[t][3] = 0.f; }
    int arow = row0 + r;
    if (arow >= N_NODES) arow = N_NODES - 1;
    const size_t abase = (size_t)arow * HIDDEN + ko;
#pragma unroll
    for (int kt = 0; kt < HIDDEN; kt += 32) {
        float4 a0 = *(const float4*)(x + abase + kt);
        float4 a1 = *(const float4*)(x + abase + kt + 4);
        bf16x8 a;
        a[0] = (__bf16)a0.x; a[1] = (__bf16)a0.y; a[2] = (__bf16)a0.z; a[3] = (__bf16)a0.w;
        a[4] = (__bf16)a1.x; a[5] = (__bf16)a1.y; a[6] = (__bf16)a1.z; a[7] = (__bf16)a1.w;
#pragma unroll
        for (int t = 0; t < 8; ++t) {
            const float* wp = W + (size_t)(t * 16 + r) * HIDDEN + kt + ko;
            float4 b0 = *(const float4*)(wp);
            float4 b1 = *(const float4*)(wp + 4);
            bf16x8 b;
            b[0] = (__bf16)b0.x; b[1] = (__bf16)b0.y; b[2] = (__bf16)b0.z; b[3] = (__bf16)b0.w;
            b[4] = (__bf16)b1.x; b[5] = (__bf16)b1.y; b[6] = (__bf16)b1.z; b[7] = (__bf16)b1.w;
            acc[t] = __builtin_amdgcn_mfma_f32_16x16x32_bf16(a, b, acc[t], 0, 0, 0);
        }
    }
    const int orow = row0 + (lane >> 4) * 4;
#pragma unroll
    for (int t = 0; t < 8; ++t) {
#pragma unroll
        for (int j = 0; j < 4; ++j) {
            int rr = orow + j;
            if (rr < N_NODES) hb[(size_t)rr * HIDDEN + t * 16 + r] = f2b(acc[t][j]);
        }
    }
}

// ---------------- packed histogram + slot capture (2 edges/thread) ----------------
__global__ void edge_hist(const int* __restrict__ dst, const float* __restrict__ w,
                          u64* __restrict__ cnt64, unsigned int* __restrict__ slot) {
    int e2 = blockIdx.x * blockDim.x + threadIdx.x;
    if (e2 >= N_EDGES / 2) return;
    int2   d2 = ((const int2*)dst)[e2];
    float2 w2 = ((const float2*)w)[e2];
    unsigned int fx0 = (unsigned int)(w2.x * FIXSCALE + 0.5f);
    unsigned int fx1 = (unsigned int)(w2.y * FIXSCALE + 0.5f);
    u64 o0 = atomicAdd(&cnt64[d2.x], (1ULL << 32) | (u64)fx0);
    u64 o1 = atomicAdd(&cnt64[d2.y], (1ULL << 32) | (u64)fx1);
    uint2 s2;
    s2.x = (unsigned int)(o0 >> 32);
    s2.y = (unsigned int)(o1 >> 32);
    ((uint2*)slot)[e2] = s2;
}

// ---------------- scan partials + dinv + graph bounds (fused) ----------------
__global__ void scan_partial(const u64* __restrict__ cnt64, int* __restrict__ bsum,
                             float* __restrict__ dinv,
                             const int* __restrict__ batch, int* __restrict__ gstart) {
    __shared__ int red[256];
    int i = blockIdx.x * 256 + threadIdx.x;
    int c = 0;
    if (i < N_NODES) {
        u64 v = cnt64[i];
        c = (int)(v >> 32);
        dinv[i] = rsqrtf(1.0f + (float)(unsigned int)v * (1.0f / FIXSCALE));
        int b0 = batch[i];
        int prev = (i == 0) ? -1 : batch[i - 1];
        for (int g = prev + 1; g <= b0; ++g) gstart[g] = i;
        if (i == N_NODES - 1) {
            for (int g = b0 + 1; g <= NUM_GRAPHS; ++g) gstart[g] = N_NODES;
        }
    }
    red[threadIdx.x] = c;
    __syncthreads();
    for (int off = 128; off > 0; off >>= 1) {
        if (threadIdx.x < off) red[threadIdx.x] += red[threadIdx.x + off];
        __syncthreads();
    }
    if (threadIdx.x == 0) bsum[blockIdx.x] = red[0];
}

__global__ void scan_bsums(const int* __restrict__ bsum, int* __restrict__ boff, int nblocks) {
    __shared__ int s[256];
    int t = threadIdx.x;
    int v0 = (t < nblocks) ? bsum[t] : 0;
    s[t] = v0;
    __syncthreads();
    for (int off = 1; off < 256; off <<= 1) {
        int v = (t >= off) ? s[t - off] : 0;
        __syncthreads();
        s[t] += v;
        __syncthreads();
    }
    boff[t] = s[t] - v0;   // exclusive
}

__global__ void scan_emit(const u64* __restrict__ cnt64, const int* __restrict__ boff,
                          int* __restrict__ rowstart) {
    __shared__ int s[256];
    int t = threadIdx.x;
    int i = blockIdx.x * 256 + t;
    int v0 = (i < N_NODES) ? (int)(cnt64[i] >> 32) : 0;
    s[t] = v0;
    __syncthreads();
    for (int off = 1; off < 256; off <<= 1) {
        int v = (t >= off) ? s[t - off] : 0;
        __syncthreads();
        s[t] += v;
        __syncthreads();
    }
    if (i < N_NODES) rowstart[i] = boff[blockIdx.x] + s[t] - v0;
    if (i == N_NODES) rowstart[N_NODES] = N_EDGES;
}

// ---------------- fill CSR: atomic-free, uses precomputed slot (2 edges/thread) ----------------
__global__ void csr_fill(const int* __restrict__ src, const int* __restrict__ dst,
                         const float* __restrict__ w, const float* __restrict__ dinv,
                         const int* __restrict__ rowstart, const unsigned int* __restrict__ slot,
                         u64* __restrict__ epack) {
    int e2 = blockIdx.x * blockDim.x + threadIdx.x;
    if (e2 >= N_EDGES / 2) return;
    int2   s2 = ((const int2*)src)[e2];
    int2   d2 = ((const int2*)dst)[e2];
    float2 w2 = ((const float2*)w)[e2];
    uint2  r2 = ((const uint2*)slot)[e2];
    float nm0 = dinv[s2.x] * w2.x * dinv[d2.x];
    float nm1 = dinv[s2.y] * w2.y * dinv[d2.y];
    int pos0 = rowstart[d2.x] + (int)r2.x;
    int pos1 = rowstart[d2.y] + (int)r2.y;
    epack[pos0] = (u64)(unsigned int)s2.x | ((u64)__float_as_uint(nm0) << 32);
    epack[pos1] = (u64)(unsigned int)s2.y | ((u64)__float_as_uint(nm1) << 32);
}

// ---------------- gather: 16 lanes/node, 16B row loads ----------------
__global__ __launch_bounds__(256) void gather_fused(const unsigned short* __restrict__ hb,
                                                    const int* __restrict__ rowstart,
                                                    const u64* __restrict__ epack,
                                                    const float* __restrict__ dinv,
                                                    const float* __restrict__ b,
                                                    float* __restrict__ out) {
    const int t = threadIdx.x;
    const int n = blockIdx.x * 16 + (t >> 4);
    if (n >= N_NODES) return;
    const int c8 = (t & 15) * 8;
    const int s0 = rowstart[n];
    const int e0 = rowstart[n + 1];
    const float di = dinv[n];
    const float sl = di * di;
    float acc[8];
    {
        u16x8 hv = *(const u16x8*)(hb + (size_t)n * HIDDEN + c8);
#pragma unroll
        for (int j = 0; j < 8; ++j) acc[j] = sl * b2f(hv[j]);
    }
    int p = s0;
    for (; p + 2 <= e0; p += 2) {
        u64 e1 = epack[p];
        u64 e2 = epack[p + 1];
        int   s1 = (int)(unsigned int)e1;
        float n1 = __uint_as_float((unsigned int)(e1 >> 32));
        int   sg2 = (int)(unsigned int)e2;
        float n2 = __uint_as_float((unsigned int)(e2 >> 32));
        u16x8 v1 = *(const u16x8*)(hb + (size_t)s1 * HIDDEN + c8);
        u16x8 v2 = *(const u16x8*)(hb + (size_t)sg2 * HIDDEN + c8);
#pragma unroll
        for (int j = 0; j < 8; ++j) acc[j] = fmaf(n1, b2f(v1[j]), acc[j]);
#pragma unroll
        for (int j = 0; j < 8; ++j) acc[j] = fmaf(n2, b2f(v2[j]), acc[j]);
    }
    if (p < e0) {
        u64 e1 = epack[p];
        int   s1 = (int)(unsigned int)e1;
        float n1 = __uint_as_float((unsigned int)(e1 >> 32));
        u16x8 v1 = *(const u16x8*)(hb + (size_t)s1 * HIDDEN + c8);
#pragma unroll
        for (int j = 0; j < 8; ++j) acc[j] = fmaf(n1, b2f(v1[j]), acc[j]);
    }
    float4 b0 = *(const float4*)(b + c8);
    float4 b1 = *(const float4*)(b + c8 + 4);
    float4 o0, o1;
    o0.x = acc[0] + b0.x; o0.y = acc[1] + b0.y; o0.z = acc[2] + b0.z; o0.w = acc[3] + b0.w;
    o1.x = acc[4] + b1.x; o1.y = acc[5] + b1.y; o1.z = acc[6] + b1.z; o1.w = acc[7] + b1.w;
    *(float4*)(out + (size_t)n * HIDDEN + c8)     = o0;
    *(float4*)(out + (size_t)n * HIDDEN + c8 + 4) = o1;
}

// ---------------- per-graph stats -> scale/shift ----------------
__global__ __launch_bounds__(256) void graph_stats(const float* __restrict__ out,
                                                   const int* __restrict__ gstart,
                                                   const float* __restrict__ ms,
                                                   const float* __restrict__ gw,
                                                   const float* __restrict__ gb,
                                                   float* __restrict__ scale,
                                                   float* __restrict__ shift) {
    const int g = blockIdx.x >> 2;
    const int q = blockIdx.x & 3;
    const int c = q * 32 + (threadIdx.x & 31);
    const int r = threadIdx.x >> 5;
    const int s = gstart[g];
    const int e = gstart[g + 1];
    float sum = 0.f, sq = 0.f;
    for (int n = s + r; n < e; n += 8) {
        float v = out[(size_t)n * HIDDEN + c];
        sum += v;
        sq = fmaf(v, v, sq);
    }
    __shared__ float ssum[8][32], ssq[8][32];
    ssum[r][threadIdx.x & 31] = sum;
    ssq[r][threadIdx.x & 31]  = sq;
    __syncthreads();
    if (r == 0) {
        int l = threadIdx.x & 31;
#pragma unroll
        for (int i = 1; i < 8; ++i) { sum += ssum[i][l]; sq += ssq[i][l]; }
        float cnt  = (float)max(e - s, 1);
        float mean = sum / cnt;
        float m2   = sq / cnt;
        float msv  = ms[c];
        float var  = fmaxf(m2 - mean * mean * msv * (2.f - msv), 0.f);
        float a    = gw[c] * rsqrtf(var + EPS_GN);
        scale[g * HIDDEN + c] = a;
        shift[g * HIDDEN + c] = gb[c] - a * msv * mean;
    }
}

// ---------------- normalize + affine + relu ----------------
__global__ __launch_bounds__(256) void gn_final(float* __restrict__ out,
                                                const float* __restrict__ scale,
                                                const float* __restrict__ shift,
                                                const int* __restrict__ batch) {
    int idx = blockIdx.x * blockDim.x + threadIdx.x;
    if (idx >= N_NODES * 32) return;
    int n  = idx >> 5;
    int c4 = (idx & 31) * 4;
    int g  = batch[n];
    float4 v  = *(float4*)(out + (size_t)n * HIDDEN + c4);
    float4 a  = *(const float4*)(scale + (size_t)g * HIDDEN + c4);
    float4 s  = *(const float4*)(shift + (size_t)g * HIDDEN + c4);
    v.x = fmaxf(fmaf(a.x, v.x, s.x), 0.f);
    v.y = fmaxf(fmaf(a.y, v.y, s.y), 0.f);
    v.z = fmaxf(fmaf(a.z, v.z, s.z), 0.f);
    v.w = fmaxf(fmaf(a.w, v.w, s.w), 0.f);
    *(float4*)(out + (size_t)n * HIDDEN + c4) = v;
}

extern "C" void kernel_launch(void* const* d_in, const int* in_sizes, int n_in,
                              void* d_out, int out_size, void* d_ws, size_t ws_size,
                              hipStream_t stream) {
    const float* node  = (const float*)d_in[0];
    const int*   ei    = (const int*)d_in[1];
    const float* eattr = (const float*)d_in[2];
    const int*   batch = (const int*)d_in[3];
    const float* W     = (const float*)d_in[4];
    const float* b     = (const float*)d_in[5];
    const float* gnw   = (const float*)d_in[6];
    const float* gnb   = (const float*)d_in[7];
    const float* gnms  = (const float*)d_in[8];
    float* out = (float*)d_out;
    float* ws  = (float*)d_ws;

    const int* src = ei;
    const int* dst = ei + N_EDGES;

    unsigned short* hb = (unsigned short*)(ws + HB_OFF);
    u64*   cnt64   = (u64*)(ws + CNT64_OFF);
    float* dinv    = ws + DINV_OFF;
    float* scale   = ws + SCALE_OFF;
    float* shift   = ws + SHIFT_OFF;
    int*   gstart  = (int*)(ws + GSTART_OFF);
    int*   rowstart= (int*)(ws + ROWS_OFF);
    int*   bsum    = (int*)(ws + BSUM_OFF);
    int*   boff    = (int*)(ws + BOFF_OFF);
    u64*   epack   = (u64*)(ws + EPACK_OFF);
    unsigned int* slot = (unsigned int*)(ws + SLOT_OFF);

    const int NB = (N_NODES + 255) / 256;   // 196

    gemm_mfma<<<(N_NODES + 63) / 64, 256, 0, stream>>>(node, W, hb, (unsigned int*)cnt64);
    edge_hist<<<(N_EDGES / 2 + 255) / 256, 256, 0, stream>>>(dst, eattr, cnt64, slot);
    scan_partial<<<NB, 256, 0, stream>>>(cnt64, bsum, dinv, batch, gstart);
    scan_bsums<<<1, 256, 0, stream>>>(bsum, boff, NB);
    scan_emit<<<NB, 256, 0, stream>>>(cnt64, boff, rowstart);
    csr_fill<<<(N_EDGES / 2 + 255) / 256, 256, 0, stream>>>(src, dst, eattr, dinv, rowstart, slot, epack);
    gather_fused<<<(N_NODES + 15) / 16, 256, 0, stream>>>(hb, rowstart, epack, dinv, b, out);
    graph_stats<<<NUM_GRAPHS * 4, 256, 0, stream>>>(out, gstart, gnms, gnw, gnb, scale, shift);
    gn_final<<<(N_NODES * 32 + 255) / 256, 256, 0, stream>>>(out, scale, shift, batch);

    (void)in_sizes; (void)n_in; (void)out_size; (void)ws_size;
}

// Round 8
// 128.453 us; speedup vs baseline: 5.8782x; 1.1608x over previous
//
#include <hip/hip_runtime.h>

#define N_NODES    50000
#define N_EDGES    625000
#define HIDDEN     128
#define NUM_GRAPHS 128
#define EPS_GN     1e-5f
#define FIXSCALE   1048576.0f   // 2^20 fixed point for degree accumulation
#define NGEMM_BLK  782          // (N_NODES + 63) / 64
#define NHIST_BLK  611          // ceil(N_EDGES/4/256)

typedef __bf16 bf16x8 __attribute__((ext_vector_type(8)));
typedef float  f32x4  __attribute__((ext_vector_type(4)));
typedef unsigned short u16x8 __attribute__((ext_vector_type(8)));
typedef unsigned long long u64;

__device__ inline unsigned short f2b(float f) {
    __bf16 b = (__bf16)f;
    return __builtin_bit_cast(unsigned short, b);
}
__device__ inline float b2f(unsigned short u) {
    unsigned int x = ((unsigned int)u) << 16;
    return __builtin_bit_cast(float, x);
}

// ---- workspace layout (4B units; u64 regions at even offsets) ----
#define HB_OFF     0          // ushort[6,400,000] bf16(h)  -> 3,200,000 units
#define CNT64_OFF  3200000    // u64[50,000]                -> 100,000 units
#define DINV_OFF   3300000    // float[50,000]
#define SCALE_OFF  3350000    // float[16,384]
#define SHIFT_OFF  3366384    // float[16,384]
#define GSTART_OFF 3382768    // int[129]
#define ROWS_OFF   3383000    // int[50,001]
#define BSUM_OFF   3433100    // int[256]
#define BOFF_OFF   3433400    // int[256]
#define EPACK_OFF  3433700    // u64[625,000]               -> 1,250,000 units (even)
#define SLOT_OFF   4683700    // u32[625,000]
#define WB_OFF     5308700    // ushort[16,384] bf16(W)     -> 8,192 units
// end 5,316,892 * 4B = 21.3 MB

// ---------------- prep: zero cnt64 + convert W -> bf16 ----------------
__global__ void prep(const float* __restrict__ W, unsigned short* __restrict__ wb,
                     unsigned int* __restrict__ cntz) {
    int i = blockIdx.x * 256 + threadIdx.x;
    if (i < 2 * N_NODES) cntz[i] = 0u;
    if (i < HIDDEN * HIDDEN) wb[i] = f2b(W[i]);
}

// ---------------- fused: GEMM tiles (blocks < NGEMM_BLK) + edge histogram ----------------
__global__ __launch_bounds__(256) void gemm_hist(const float* __restrict__ x,
                                                 const unsigned short* __restrict__ wb,
                                                 unsigned short* __restrict__ hb,
                                                 const int* __restrict__ dst,
                                                 const float* __restrict__ w,
                                                 u64* __restrict__ cnt64,
                                                 unsigned int* __restrict__ slot) {
    if (blockIdx.x >= NGEMM_BLK) {
        // ---- histogram part: 4 edges/thread ----
        int base = (blockIdx.x - NGEMM_BLK) * 256 + threadIdx.x;
        if (base * 4 >= N_EDGES) return;
        int4   d4 = ((const int4*)dst)[base];
        float4 w4 = ((const float4*)w)[base];
        unsigned int fx0 = (unsigned int)(w4.x * FIXSCALE + 0.5f);
        unsigned int fx1 = (unsigned int)(w4.y * FIXSCALE + 0.5f);
        unsigned int fx2 = (unsigned int)(w4.z * FIXSCALE + 0.5f);
        unsigned int fx3 = (unsigned int)(w4.w * FIXSCALE + 0.5f);
        u64 o0 = atomicAdd(&cnt64[d4.x], (1ULL << 32) | (u64)fx0);
        u64 o1 = atomicAdd(&cnt64[d4.y], (1ULL << 32) | (u64)fx1);
        u64 o2 = atomicAdd(&cnt64[d4.z], (1ULL << 32) | (u64)fx2);
        u64 o3 = atomicAdd(&cnt64[d4.w], (1ULL << 32) | (u64)fx3);
        uint4 s4;
        s4.x = (unsigned int)(o0 >> 32);
        s4.y = (unsigned int)(o1 >> 32);
        s4.z = (unsigned int)(o2 >> 32);
        s4.w = (unsigned int)(o3 >> 32);
        ((uint4*)slot)[base] = s4;
        return;
    }
    // ---- GEMM part: h = x @ W.T ----
    const int wave = threadIdx.x >> 6;
    const int lane = threadIdx.x & 63;
    const int row0 = blockIdx.x * 64 + wave * 16;
    const int r  = lane & 15;
    const int ko = (lane >> 4) * 8;
    f32x4 acc[8];
#pragma unroll
    for (int t = 0; t < 8; ++t) { acc[t][0] = 0.f; acc[t][1] = 0.f; acc[t][2] = 0.f; acc[t][3] = 0.f; }
    int arow = row0 + r;
    if (arow >= N_NODES) arow = N_NODES - 1;
    const size_t abase = (size_t)arow * HIDDEN + ko;
#pragma unroll
    for (int kt = 0; kt < HIDDEN; kt += 32) {
        float4 a0 = *(const float4*)(x + abase + kt);
        float4 a1 = *(const float4*)(x + abase + kt + 4);
        bf16x8 a;
        a[0] = (__bf16)a0.x; a[1] = (__bf16)a0.y; a[2] = (__bf16)a0.z; a[3] = (__bf16)a0.w;
        a[4] = (__bf16)a1.x; a[5] = (__bf16)a1.y; a[6] = (__bf16)a1.z; a[7] = (__bf16)a1.w;
#pragma unroll
        for (int t = 0; t < 8; ++t) {
            bf16x8 b = *(const bf16x8*)(wb + (size_t)(t * 16 + r) * HIDDEN + kt + ko);
            acc[t] = __builtin_amdgcn_mfma_f32_16x16x32_bf16(a, b, acc[t], 0, 0, 0);
        }
    }
    const int orow = row0 + (lane >> 4) * 4;
#pragma unroll
    for (int t = 0; t < 8; ++t) {
#pragma unroll
        for (int j = 0; j < 4; ++j) {
            int rr = orow + j;
            if (rr < N_NODES) hb[(size_t)rr * HIDDEN + t * 16 + r] = f2b(acc[t][j]);
        }
    }
}

// ---------------- scan partials + dinv + graph bounds (fused) ----------------
__global__ void scan_partial(const u64* __restrict__ cnt64, int* __restrict__ bsum,
                             float* __restrict__ dinv,
                             const int* __restrict__ batch, int* __restrict__ gstart) {
    __shared__ int red[256];
    int i = blockIdx.x * 256 + threadIdx.x;
    int c = 0;
    if (i < N_NODES) {
        u64 v = cnt64[i];
        c = (int)(v >> 32);
        dinv[i] = rsqrtf(1.0f + (float)(unsigned int)v * (1.0f / FIXSCALE));
        int b0 = batch[i];
        int prev = (i == 0) ? -1 : batch[i - 1];
        for (int g = prev + 1; g <= b0; ++g) gstart[g] = i;
        if (i == N_NODES - 1) {
            for (int g = b0 + 1; g <= NUM_GRAPHS; ++g) gstart[g] = N_NODES;
        }
    }
    red[threadIdx.x] = c;
    __syncthreads();
    for (int off = 128; off > 0; off >>= 1) {
        if (threadIdx.x < off) red[threadIdx.x] += red[threadIdx.x + off];
        __syncthreads();
    }
    if (threadIdx.x == 0) bsum[blockIdx.x] = red[0];
}

__global__ void scan_bsums(const int* __restrict__ bsum, int* __restrict__ boff, int nblocks) {
    __shared__ int s[256];
    int t = threadIdx.x;
    int v0 = (t < nblocks) ? bsum[t] : 0;
    s[t] = v0;
    __syncthreads();
    for (int off = 1; off < 256; off <<= 1) {
        int v = (t >= off) ? s[t - off] : 0;
        __syncthreads();
        s[t] += v;
        __syncthreads();
    }
    boff[t] = s[t] - v0;   // exclusive
}

__global__ void scan_emit(const u64* __restrict__ cnt64, const int* __restrict__ boff,
                          int* __restrict__ rowstart) {
    __shared__ int s[256];
    int t = threadIdx.x;
    int i = blockIdx.x * 256 + t;
    int v0 = (i < N_NODES) ? (int)(cnt64[i] >> 32) : 0;
    s[t] = v0;
    __syncthreads();
    for (int off = 1; off < 256; off <<= 1) {
        int v = (t >= off) ? s[t - off] : 0;
        __syncthreads();
        s[t] += v;
        __syncthreads();
    }
    if (i < N_NODES) rowstart[i] = boff[blockIdx.x] + s[t] - v0;
    if (i == N_NODES) rowstart[N_NODES] = N_EDGES;
}

// ---------------- fill CSR: atomic-free, 4 edges/thread ----------------
__global__ void csr_fill(const int* __restrict__ src, const int* __restrict__ dst,
                         const float* __restrict__ w, const float* __restrict__ dinv,
                         const int* __restrict__ rowstart, const unsigned int* __restrict__ slot,
                         u64* __restrict__ epack) {
    int base = blockIdx.x * blockDim.x + threadIdx.x;
    if (base * 4 >= N_EDGES) return;
    int4   s4 = ((const int4*)src)[base];
    int4   d4 = ((const int4*)dst)[base];
    float4 w4 = ((const float4*)w)[base];
    uint4  r4 = ((const uint4*)slot)[base];
    float nm0 = dinv[s4.x] * w4.x * dinv[d4.x];
    float nm1 = dinv[s4.y] * w4.y * dinv[d4.y];
    float nm2 = dinv[s4.z] * w4.z * dinv[d4.z];
    float nm3 = dinv[s4.w] * w4.w * dinv[d4.w];
    epack[rowstart[d4.x] + (int)r4.x] = (u64)(unsigned int)s4.x | ((u64)__float_as_uint(nm0) << 32);
    epack[rowstart[d4.y] + (int)r4.y] = (u64)(unsigned int)s4.y | ((u64)__float_as_uint(nm1) << 32);
    epack[rowstart[d4.z] + (int)r4.z] = (u64)(unsigned int)s4.z | ((u64)__float_as_uint(nm2) << 32);
    epack[rowstart[d4.w] + (int)r4.w] = (u64)(unsigned int)s4.w | ((u64)__float_as_uint(nm3) << 32);
}

// ---------------- gather: 16 lanes/node, 16B row loads ----------------
__global__ __launch_bounds__(256) void gather_fused(const unsigned short* __restrict__ hb,
                                                    const int* __restrict__ rowstart,
                                                    const u64* __restrict__ epack,
                                                    const float* __restrict__ dinv,
                                                    const float* __restrict__ b,
                                                    float* __restrict__ out) {
    const int t = threadIdx.x;
    const int n = blockIdx.x * 16 + (t >> 4);
    if (n >= N_NODES) return;
    const int c8 = (t & 15) * 8;
    const int s0 = rowstart[n];
    const int e0 = rowstart[n + 1];
    const float di = dinv[n];
    const float sl = di * di;
    float acc[8];
    {
        u16x8 hv = *(const u16x8*)(hb + (size_t)n * HIDDEN + c8);
#pragma unroll
        for (int j = 0; j < 8; ++j) acc[j] = sl * b2f(hv[j]);
    }
    int p = s0;
    for (; p + 2 <= e0; p += 2) {
        u64 e1 = epack[p];
        u64 e2 = epack[p + 1];
        int   s1 = (int)(unsigned int)e1;
        float n1 = __uint_as_float((unsigned int)(e1 >> 32));
        int   sg2 = (int)(unsigned int)e2;
        float n2 = __uint_as_float((unsigned int)(e2 >> 32));
        u16x8 v1 = *(const u16x8*)(hb + (size_t)s1 * HIDDEN + c8);
        u16x8 v2 = *(const u16x8*)(hb + (size_t)sg2 * HIDDEN + c8);
#pragma unroll
        for (int j = 0; j < 8; ++j) acc[j] = fmaf(n1, b2f(v1[j]), acc[j]);
#pragma unroll
        for (int j = 0; j < 8; ++j) acc[j] = fmaf(n2, b2f(v2[j]), acc[j]);
    }
    if (p < e0) {
        u64 e1 = epack[p];
        int   s1 = (int)(unsigned int)e1;
        float n1 = __uint_as_float((unsigned int)(e1 >> 32));
        u16x8 v1 = *(const u16x8*)(hb + (size_t)s1 * HIDDEN + c8);
#pragma unroll
        for (int j = 0; j < 8; ++j) acc[j] = fmaf(n1, b2f(v1[j]), acc[j]);
    }
    float4 b0 = *(const float4*)(b + c8);
    float4 b1 = *(const float4*)(b + c8 + 4);
    float4 o0, o1;
    o0.x = acc[0] + b0.x; o0.y = acc[1] + b0.y; o0.z = acc[2] + b0.z; o0.w = acc[3] + b0.w;
    o1.x = acc[4] + b1.x; o1.y = acc[5] + b1.y; o1.z = acc[6] + b1.z; o1.w = acc[7] + b1.w;
    *(float4*)(out + (size_t)n * HIDDEN + c8)     = o0;
    *(float4*)(out + (size_t)n * HIDDEN + c8 + 4) = o1;
}

// ---------------- per-graph stats -> scale/shift ----------------
__global__ __launch_bounds__(256) void graph_stats(const float* __restrict__ out,
                                                   const int* __restrict__ gstart,
                                                   const float* __restrict__ ms,
                                                   const float* __restrict__ gw,
                                                   const float* __restrict__ gb,
                                                   float* __restrict__ scale,
                                                   float* __restrict__ shift) {
    const int g = blockIdx.x >> 2;
    const int q = blockIdx.x & 3;
    const int c = q * 32 + (threadIdx.x & 31);
    const int r = threadIdx.x >> 5;
    const int s = gstart[g];
    const int e = gstart[g + 1];
    float sum = 0.f, sq = 0.f;
    for (int n = s + r; n < e; n += 8) {
        float v = out[(size_t)n * HIDDEN + c];
        sum += v;
        sq = fmaf(v, v, sq);
    }
    __shared__ float ssum[8][32], ssq[8][32];
    ssum[r][threadIdx.x & 31] = sum;
    ssq[r][threadIdx.x & 31]  = sq;
    __syncthreads();
    if (r == 0) {
        int l = threadIdx.x & 31;
#pragma unroll
        for (int i = 1; i < 8; ++i) { sum += ssum[i][l]; sq += ssq[i][l]; }
        float cnt  = (float)max(e - s, 1);
        float mean = sum / cnt;
        float m2   = sq / cnt;
        float msv  = ms[c];
        float var  = fmaxf(m2 - mean * mean * msv * (2.f - msv), 0.f);
        float a    = gw[c] * rsqrtf(var + EPS_GN);
        scale[g * HIDDEN + c] = a;
        shift[g * HIDDEN + c] = gb[c] - a * msv * mean;
    }
}

// ---------------- normalize + affine + relu ----------------
__global__ __launch_bounds__(256) void gn_final(float* __restrict__ out,
                                                const float* __restrict__ scale,
                                                const float* __restrict__ shift,
                                                const int* __restrict__ batch) {
    int idx = blockIdx.x * blockDim.x + threadIdx.x;
    if (idx >= N_NODES * 32) return;
    int n  = idx >> 5;
    int c4 = (idx & 31) * 4;
    int g  = batch[n];
    float4 v  = *(float4*)(out + (size_t)n * HIDDEN + c4);
    float4 a  = *(const float4*)(scale + (size_t)g * HIDDEN + c4);
    float4 s  = *(const float4*)(shift + (size_t)g * HIDDEN + c4);
    v.x = fmaxf(fmaf(a.x, v.x, s.x), 0.f);
    v.y = fmaxf(fmaf(a.y, v.y, s.y), 0.f);
    v.z = fmaxf(fmaf(a.z, v.z, s.z), 0.f);
    v.w = fmaxf(fmaf(a.w, v.w, s.w), 0.f);
    *(float4*)(out + (size_t)n * HIDDEN + c4) = v;
}

extern "C" void kernel_launch(void* const* d_in, const int* in_sizes, int n_in,
                              void* d_out, int out_size, void* d_ws, size_t ws_size,
                              hipStream_t stream) {
    const float* node  = (const float*)d_in[0];
    const int*   ei    = (const int*)d_in[1];
    const float* eattr = (const float*)d_in[2];
    const int*   batch = (const int*)d_in[3];
    const float* W     = (const float*)d_in[4];
    const float* b     = (const float*)d_in[5];
    const float* gnw   = (const float*)d_in[6];
    const float* gnb   = (const float*)d_in[7];
    const float* gnms  = (const float*)d_in[8];
    float* out = (float*)d_out;
    float* ws  = (float*)d_ws;

    const int* src = ei;
    const int* dst = ei + N_EDGES;

    unsigned short* hb = (unsigned short*)(ws + HB_OFF);
    u64*   cnt64   = (u64*)(ws + CNT64_OFF);
    float* dinv    = ws + DINV_OFF;
    float* scale   = ws + SCALE_OFF;
    float* shift   = ws + SHIFT_OFF;
    int*   gstart  = (int*)(ws + GSTART_OFF);
    int*   rowstart= (int*)(ws + ROWS_OFF);
    int*   bsum    = (int*)(ws + BSUM_OFF);
    int*   boff    = (int*)(ws + BOFF_OFF);
    u64*   epack   = (u64*)(ws + EPACK_OFF);
    unsigned int* slot = (unsigned int*)(ws + SLOT_OFF);
    unsigned short* wb = (unsigned short*)(ws + WB_OFF);

    const int NB = (N_NODES + 255) / 256;   // 196

    prep<<<(2 * N_NODES + 255) / 256, 256, 0, stream>>>(W, wb, (unsigned int*)cnt64);
    gemm_hist<<<NGEMM_BLK + NHIST_BLK, 256, 0, stream>>>(node, wb, hb, dst, eattr, cnt64, slot);
    scan_partial<<<NB, 256, 0, stream>>>(cnt64, bsum, dinv, batch, gstart);
    scan_bsums<<<1, 256, 0, stream>>>(bsum, boff, NB);
    scan_emit<<<NB, 256, 0, stream>>>(cnt64, boff, rowstart);
    csr_fill<<<NHIST_BLK, 256, 0, stream>>>(src, dst, eattr, dinv, rowstart, slot, epack);
    gather_fused<<<(N_NODES + 15) / 16, 256, 0, stream>>>(hb, rowstart, epack, dinv, b, out);
    graph_stats<<<NUM_GRAPHS * 4, 256, 0, stream>>>(out, gstart, gnms, gnw, gnb, scale, shift);
    gn_final<<<(N_NODES * 32 + 255) / 256, 256, 0, stream>>>(out, scale, shift, batch);

    (void)in_sizes; (void)n_in; (void)out_size; (void)ws_size;
}

// Round 9
// 128.388 us; speedup vs baseline: 5.8811x; 1.0005x over previous
//
#include <hip/hip_runtime.h>

#define N_NODES    50000
#define N_EDGES    625000
#define HIDDEN     128
#define NUM_GRAPHS 128
#define EPS_GN     1e-5f
#define FIXSCALE   1048576.0f   // 2^20 fixed point for degree accumulation
#define NGEMM_BLK  782          // (N_NODES + 63) / 64
#define NHIST_BLK  611          // ceil(N_EDGES/4/256)
#define CPAD       8            // counters padded to one per 64B cacheline

typedef __bf16 bf16x8 __attribute__((ext_vector_type(8)));
typedef float  f32x4  __attribute__((ext_vector_type(4)));
typedef unsigned short u16x8 __attribute__((ext_vector_type(8)));
typedef unsigned long long u64;

__device__ inline unsigned short f2b(float f) {
    __bf16 b = (__bf16)f;
    return __builtin_bit_cast(unsigned short, b);
}
__device__ inline float b2f(unsigned short u) {
    unsigned int x = ((unsigned int)u) << 16;
    return __builtin_bit_cast(float, x);
}

// ---- workspace layout (4B units; u64 regions at even offsets) ----
#define HB_OFF     0          // ushort[6,400,000] bf16(h)   -> 3,200,000 units
#define CNT64_OFF  3200000    // u64[50,000 * 8] padded      -> 800,000 units
#define DINV_OFF   4000000    // float[50,000]
#define SCALE_OFF  4050000    // float[16,384]
#define SHIFT_OFF  4066384    // float[16,384]
#define GSTART_OFF 4082768    // int[129]
#define ROWS_OFF   4083000    // int[50,001]
#define BSUM_OFF   4133100    // int[256]
#define BOFF_OFF   4133400    // int[256]
#define EPACK_OFF  4133700    // u64[625,000]                -> 1,250,000 units (even)
#define SLOT_OFF   5383700    // u32[625,000]
#define WB_OFF     6008700    // ushort[16,384] bf16(W)      -> 8,192 units
// end 6,016,892 * 4B = 24.1 MB

// ---------------- prep: zero padded cnt64 region + convert W -> bf16 ----------------
__global__ void prep(const float* __restrict__ W, unsigned short* __restrict__ wb,
                     uint4* __restrict__ cntz) {
    int i = blockIdx.x * 256 + threadIdx.x;
    if (i < 800000 / 4) cntz[i] = make_uint4(0u, 0u, 0u, 0u);
    if (i < HIDDEN * HIDDEN) wb[i] = f2b(W[i]);
}

// ---------------- fused: GEMM tiles (blocks < NGEMM_BLK) + edge histogram ----------------
__global__ __launch_bounds__(256) void gemm_hist(const float* __restrict__ x,
                                                 const unsigned short* __restrict__ wb,
                                                 unsigned short* __restrict__ hb,
                                                 const int* __restrict__ dst,
                                                 const float* __restrict__ w,
                                                 u64* __restrict__ cnt64,
                                                 unsigned int* __restrict__ slot) {
    if (blockIdx.x >= NGEMM_BLK) {
        // ---- histogram part: 4 edges/thread, line-padded counters ----
        int base = (blockIdx.x - NGEMM_BLK) * 256 + threadIdx.x;
        if (base * 4 >= N_EDGES) return;
        int4   d4 = ((const int4*)dst)[base];
        float4 w4 = ((const float4*)w)[base];
        unsigned int fx0 = (unsigned int)(w4.x * FIXSCALE + 0.5f);
        unsigned int fx1 = (unsigned int)(w4.y * FIXSCALE + 0.5f);
        unsigned int fx2 = (unsigned int)(w4.z * FIXSCALE + 0.5f);
        unsigned int fx3 = (unsigned int)(w4.w * FIXSCALE + 0.5f);
        u64 o0 = atomicAdd(&cnt64[(size_t)d4.x * CPAD], (1ULL << 32) | (u64)fx0);
        u64 o1 = atomicAdd(&cnt64[(size_t)d4.y * CPAD], (1ULL << 32) | (u64)fx1);
        u64 o2 = atomicAdd(&cnt64[(size_t)d4.z * CPAD], (1ULL << 32) | (u64)fx2);
        u64 o3 = atomicAdd(&cnt64[(size_t)d4.w * CPAD], (1ULL << 32) | (u64)fx3);
        uint4 s4;
        s4.x = (unsigned int)(o0 >> 32);
        s4.y = (unsigned int)(o1 >> 32);
        s4.z = (unsigned int)(o2 >> 32);
        s4.w = (unsigned int)(o3 >> 32);
        ((uint4*)slot)[base] = s4;
        return;
    }
    // ---- GEMM part: h = x @ W.T ----
    const int wave = threadIdx.x >> 6;
    const int lane = threadIdx.x & 63;
    const int row0 = blockIdx.x * 64 + wave * 16;
    const int r  = lane & 15;
    const int ko = (lane >> 4) * 8;
    f32x4 acc[8];
#pragma unroll
    for (int t = 0; t < 8; ++t) { acc[t][0] = 0.f; acc[t][1] = 0.f; acc[t][2] = 0.f; acc[t][3] = 0.f; }
    int arow = row0 + r;
    if (arow >= N_NODES) arow = N_NODES - 1;
    const size_t abase = (size_t)arow * HIDDEN + ko;
#pragma unroll
    for (int kt = 0; kt < HIDDEN; kt += 32) {
        float4 a0 = *(const float4*)(x + abase + kt);
        float4 a1 = *(const float4*)(x + abase + kt + 4);
        bf16x8 a;
        a[0] = (__bf16)a0.x; a[1] = (__bf16)a0.y; a[2] = (__bf16)a0.z; a[3] = (__bf16)a0.w;
        a[4] = (__bf16)a1.x; a[5] = (__bf16)a1.y; a[6] = (__bf16)a1.z; a[7] = (__bf16)a1.w;
#pragma unroll
        for (int t = 0; t < 8; ++t) {
            bf16x8 b = *(const bf16x8*)(wb + (size_t)(t * 16 + r) * HIDDEN + kt + ko);
            acc[t] = __builtin_amdgcn_mfma_f32_16x16x32_bf16(a, b, acc[t], 0, 0, 0);
        }
    }
    const int orow = row0 + (lane >> 4) * 4;
#pragma unroll
    for (int t = 0; t < 8; ++t) {
#pragma unroll
        for (int j = 0; j < 4; ++j) {
            int rr = orow + j;
            if (rr < N_NODES) hb[(size_t)rr * HIDDEN + t * 16 + r] = f2b(acc[t][j]);
        }
    }
}

// ---------------- scan partials + dinv + graph bounds (fused) ----------------
__global__ void scan_partial(const u64* __restrict__ cnt64, int* __restrict__ bsum,
                             float* __restrict__ dinv,
                             const int* __restrict__ batch, int* __restrict__ gstart) {
    __shared__ int red[256];
    int i = blockIdx.x * 256 + threadIdx.x;
    int c = 0;
    if (i < N_NODES) {
        u64 v = cnt64[(size_t)i * CPAD];
        c = (int)(v >> 32);
        dinv[i] = rsqrtf(1.0f + (float)(unsigned int)v * (1.0f / FIXSCALE));
        int b0 = batch[i];
        int prev = (i == 0) ? -1 : batch[i - 1];
        for (int g = prev + 1; g <= b0; ++g) gstart[g] = i;
        if (i == N_NODES - 1) {
            for (int g = b0 + 1; g <= NUM_GRAPHS; ++g) gstart[g] = N_NODES;
        }
    }
    red[threadIdx.x] = c;
    __syncthreads();
    for (int off = 128; off > 0; off >>= 1) {
        if (threadIdx.x < off) red[threadIdx.x] += red[threadIdx.x + off];
        __syncthreads();
    }
    if (threadIdx.x == 0) bsum[blockIdx.x] = red[0];
}

__global__ void scan_bsums(const int* __restrict__ bsum, int* __restrict__ boff, int nblocks) {
    __shared__ int s[256];
    int t = threadIdx.x;
    int v0 = (t < nblocks) ? bsum[t] : 0;
    s[t] = v0;
    __syncthreads();
    for (int off = 1; off < 256; off <<= 1) {
        int v = (t >= off) ? s[t - off] : 0;
        __syncthreads();
        s[t] += v;
        __syncthreads();
    }
    boff[t] = s[t] - v0;   // exclusive
}

__global__ void scan_emit(const u64* __restrict__ cnt64, const int* __restrict__ boff,
                          int* __restrict__ rowstart) {
    __shared__ int s[256];
    int t = threadIdx.x;
    int i = blockIdx.x * 256 + t;
    int v0 = (i < N_NODES) ? (int)(cnt64[(size_t)i * CPAD] >> 32) : 0;
    s[t] = v0;
    __syncthreads();
    for (int off = 1; off < 256; off <<= 1) {
        int v = (t >= off) ? s[t - off] : 0;
        __syncthreads();
        s[t] += v;
        __syncthreads();
    }
    if (i < N_NODES) rowstart[i] = boff[blockIdx.x] + s[t] - v0;
    if (i == N_NODES) rowstart[N_NODES] = N_EDGES;
}

// ---------------- fill CSR: atomic-free, 4 edges/thread ----------------
__global__ void csr_fill(const int* __restrict__ src, const int* __restrict__ dst,
                         const float* __restrict__ w, const float* __restrict__ dinv,
                         const int* __restrict__ rowstart, const unsigned int* __restrict__ slot,
                         u64* __restrict__ epack) {
    int base = blockIdx.x * blockDim.x + threadIdx.x;
    if (base * 4 >= N_EDGES) return;
    int4   s4 = ((const int4*)src)[base];
    int4   d4 = ((const int4*)dst)[base];
    float4 w4 = ((const float4*)w)[base];
    uint4  r4 = ((const uint4*)slot)[base];
    float nm0 = dinv[s4.x] * w4.x * dinv[d4.x];
    float nm1 = dinv[s4.y] * w4.y * dinv[d4.y];
    float nm2 = dinv[s4.z] * w4.z * dinv[d4.z];
    float nm3 = dinv[s4.w] * w4.w * dinv[d4.w];
    epack[rowstart[d4.x] + (int)r4.x] = (u64)(unsigned int)s4.x | ((u64)__float_as_uint(nm0) << 32);
    epack[rowstart[d4.y] + (int)r4.y] = (u64)(unsigned int)s4.y | ((u64)__float_as_uint(nm1) << 32);
    epack[rowstart[d4.z] + (int)r4.z] = (u64)(unsigned int)s4.z | ((u64)__float_as_uint(nm2) << 32);
    epack[rowstart[d4.w] + (int)r4.w] = (u64)(unsigned int)s4.w | ((u64)__float_as_uint(nm3) << 32);
}

// ---------------- gather: 16 lanes/node, 16B row loads ----------------
__global__ __launch_bounds__(256) void gather_fused(const unsigned short* __restrict__ hb,
                                                    const int* __restrict__ rowstart,
                                                    const u64* __restrict__ epack,
                                                    const float* __restrict__ dinv,
                                                    const float* __restrict__ b,
                                                    float* __restrict__ out) {
    const int t = threadIdx.x;
    const int n = blockIdx.x * 16 + (t >> 4);
    if (n >= N_NODES) return;
    const int c8 = (t & 15) * 8;
    const int s0 = rowstart[n];
    const int e0 = rowstart[n + 1];
    const float di = dinv[n];
    const float sl = di * di;
    float acc[8];
    {
        u16x8 hv = *(const u16x8*)(hb + (size_t)n * HIDDEN + c8);
#pragma unroll
        for (int j = 0; j < 8; ++j) acc[j] = sl * b2f(hv[j]);
    }
    int p = s0;
    for (; p + 2 <= e0; p += 2) {
        u64 e1 = epack[p];
        u64 e2 = epack[p + 1];
        int   s1 = (int)(unsigned int)e1;
        float n1 = __uint_as_float((unsigned int)(e1 >> 32));
        int   sg2 = (int)(unsigned int)e2;
        float n2 = __uint_as_float((unsigned int)(e2 >> 32));
        u16x8 v1 = *(const u16x8*)(hb + (size_t)s1 * HIDDEN + c8);
        u16x8 v2 = *(const u16x8*)(hb + (size_t)sg2 * HIDDEN + c8);
#pragma unroll
        for (int j = 0; j < 8; ++j) acc[j] = fmaf(n1, b2f(v1[j]), acc[j]);
#pragma unroll
        for (int j = 0; j < 8; ++j) acc[j] = fmaf(n2, b2f(v2[j]), acc[j]);
    }
    if (p < e0) {
        u64 e1 = epack[p];
        int   s1 = (int)(unsigned int)e1;
        float n1 = __uint_as_float((unsigned int)(e1 >> 32));
        u16x8 v1 = *(const u16x8*)(hb + (size_t)s1 * HIDDEN + c8);
#pragma unroll
        for (int j = 0; j < 8; ++j) acc[j] = fmaf(n1, b2f(v1[j]), acc[j]);
    }
    float4 b0 = *(const float4*)(b + c8);
    float4 b1 = *(const float4*)(b + c8 + 4);
    float4 o0, o1;
    o0.x = acc[0] + b0.x; o0.y = acc[1] + b0.y; o0.z = acc[2] + b0.z; o0.w = acc[3] + b0.w;
    o1.x = acc[4] + b1.x; o1.y = acc[5] + b1.y; o1.z = acc[6] + b1.z; o1.w = acc[7] + b1.w;
    *(float4*)(out + (size_t)n * HIDDEN + c8)     = o0;
    *(float4*)(out + (size_t)n * HIDDEN + c8 + 4) = o1;
}

// ---------------- per-graph stats -> scale/shift ----------------
__global__ __launch_bounds__(256) void graph_stats(const float* __restrict__ out,
                                                   const int* __restrict__ gstart,
                                                   const float* __restrict__ ms,
                                                   const float* __restrict__ gw,
                                                   const float* __restrict__ gb,
                                                   float* __restrict__ scale,
                                                   float* __restrict__ shift) {
    const int g = blockIdx.x >> 2;
    const int q = blockIdx.x & 3;
    const int c = q * 32 + (threadIdx.x & 31);
    const int r = threadIdx.x >> 5;
    const int s = gstart[g];
    const int e = gstart[g + 1];
    float sum = 0.f, sq = 0.f;
    for (int n = s + r; n < e; n += 8) {
        float v = out[(size_t)n * HIDDEN + c];
        sum += v;
        sq = fmaf(v, v, sq);
    }
    __shared__ float ssum[8][32], ssq[8][32];
    ssum[r][threadIdx.x & 31] = sum;
    ssq[r][threadIdx.x & 31]  = sq;
    __syncthreads();
    if (r == 0) {
        int l = threadIdx.x & 31;
#pragma unroll
        for (int i = 1; i < 8; ++i) { sum += ssum[i][l]; sq += ssq[i][l]; }
        float cnt  = (float)max(e - s, 1);
        float mean = sum / cnt;
        float m2   = sq / cnt;
        float msv  = ms[c];
        float var  = fmaxf(m2 - mean * mean * msv * (2.f - msv), 0.f);
        float a    = gw[c] * rsqrtf(var + EPS_GN);
        scale[g * HIDDEN + c] = a;
        shift[g * HIDDEN + c] = gb[c] - a * msv * mean;
    }
}

// ---------------- normalize + affine + relu ----------------
__global__ __launch_bounds__(256) void gn_final(float* __restrict__ out,
                                                const float* __restrict__ scale,
                                                const float* __restrict__ shift,
                                                const int* __restrict__ batch) {
    int idx = blockIdx.x * blockDim.x + threadIdx.x;
    if (idx >= N_NODES * 32) return;
    int n  = idx >> 5;
    int c4 = (idx & 31) * 4;
    int g  = batch[n];
    float4 v  = *(float4*)(out + (size_t)n * HIDDEN + c4);
    float4 a  = *(const float4*)(scale + (size_t)g * HIDDEN + c4);
    float4 s  = *(const float4*)(shift + (size_t)g * HIDDEN + c4);
    v.x = fmaxf(fmaf(a.x, v.x, s.x), 0.f);
    v.y = fmaxf(fmaf(a.y, v.y, s.y), 0.f);
    v.z = fmaxf(fmaf(a.z, v.z, s.z), 0.f);
    v.w = fmaxf(fmaf(a.w, v.w, s.w), 0.f);
    *(float4*)(out + (size_t)n * HIDDEN + c4) = v;
}

extern "C" void kernel_launch(void* const* d_in, const int* in_sizes, int n_in,
                              void* d_out, int out_size, void* d_ws, size_t ws_size,
                              hipStream_t stream) {
    const float* node  = (const float*)d_in[0];
    const int*   ei    = (const int*)d_in[1];
    const float* eattr = (const float*)d_in[2];
    const int*   batch = (const int*)d_in[3];
    const float* W     = (const float*)d_in[4];
    const float* b     = (const float*)d_in[5];
    const float* gnw   = (const float*)d_in[6];
    const float* gnb   = (const float*)d_in[7];
    const float* gnms  = (const float*)d_in[8];
    float* out = (float*)d_out;
    float* ws  = (float*)d_ws;

    const int* src = ei;
    const int* dst = ei + N_EDGES;

    unsigned short* hb = (unsigned short*)(ws + HB_OFF);
    u64*   cnt64   = (u64*)(ws + CNT64_OFF);
    float* dinv    = ws + DINV_OFF;
    float* scale   = ws + SCALE_OFF;
    float* shift   = ws + SHIFT_OFF;
    int*   gstart  = (int*)(ws + GSTART_OFF);
    int*   rowstart= (int*)(ws + ROWS_OFF);
    int*   bsum    = (int*)(ws + BSUM_OFF);
    int*   boff    = (int*)(ws + BOFF_OFF);
    u64*   epack   = (u64*)(ws + EPACK_OFF);
    unsigned int* slot = (unsigned int*)(ws + SLOT_OFF);
    unsigned short* wb = (unsigned short*)(ws + WB_OFF);

    const int NB = (N_NODES + 255) / 256;   // 196

    prep<<<(200000 + 255) / 256, 256, 0, stream>>>(W, wb, (uint4*)cnt64);
    gemm_hist<<<NGEMM_BLK + NHIST_BLK, 256, 0, stream>>>(node, wb, hb, dst, eattr, cnt64, slot);
    scan_partial<<<NB, 256, 0, stream>>>(cnt64, bsum, dinv, batch, gstart);
    scan_bsums<<<1, 256, 0, stream>>>(bsum, boff, NB);
    scan_emit<<<NB, 256, 0, stream>>>(cnt64, boff, rowstart);
    csr_fill<<<NHIST_BLK, 256, 0, stream>>>(src, dst, eattr, dinv, rowstart, slot, epack);
    gather_fused<<<(N_NODES + 15) / 16, 256, 0, stream>>>(hb, rowstart, epack, dinv, b, out);
    graph_stats<<<NUM_GRAPHS * 4, 256, 0, stream>>>(out, gstart, gnms, gnw, gnb, scale, shift);
    gn_final<<<(N_NODES * 32 + 255) / 256, 256, 0, stream>>>(out, scale, shift, batch);

    (void)in_sizes; (void)n_in; (void)out_size; (void)ws_size;
}